// Round 1
// baseline (807.867 us; speedup 1.0000x reference)
//
#include <hip/hip_runtime.h>
#include <cstdint>
#include <cstddef>

static constexpr int N_NODES = 100000;
static constexpr int N_EDGES = 600000;
static constexpr int E_TOT   = N_EDGES + N_NODES;
static constexpr float NEG_SLOPE = 0.2f;

__device__ __forceinline__ float leaky(float x) { return x >= 0.f ? x : NEG_SLOPE * x; }

// ---------------- CSR build ----------------

__global__ __launch_bounds__(256) void k_init_counts(int* __restrict__ counts) {
  int i = blockIdx.x * 256 + threadIdx.x;
  if (i < N_NODES) counts[i] = 1;   // self-loop
}

__global__ __launch_bounds__(256) void k_hist(const int* __restrict__ ei, int* __restrict__ counts) {
  int e = blockIdx.x * 256 + threadIdx.x;
  if (e < N_EDGES) atomicAdd(&counts[ei[N_EDGES + e]], 1);
}

__global__ __launch_bounds__(256) void k_scan1(const int* __restrict__ counts,
                                               int* __restrict__ partial,
                                               int* __restrict__ blockSums) {
  __shared__ int tmp[256];
  int tid = threadIdx.x;
  int i = blockIdx.x * 256 + tid;
  int v = (i < N_NODES) ? counts[i] : 0;
  tmp[tid] = v;
  __syncthreads();
  for (int off = 1; off < 256; off <<= 1) {
    int t = (tid >= off) ? tmp[tid - off] : 0;
    __syncthreads();
    tmp[tid] += t;
    __syncthreads();
  }
  if (i < N_NODES) partial[i] = tmp[tid] - v;   // exclusive within block
  if (tid == 255) blockSums[blockIdx.x] = tmp[tid];
}

__global__ __launch_bounds__(512) void k_scan2(int* __restrict__ blockSums, int nb) {
  __shared__ int tmp[512];
  int tid = threadIdx.x;
  int v = (tid < nb) ? blockSums[tid] : 0;
  tmp[tid] = v;
  __syncthreads();
  for (int off = 1; off < 512; off <<= 1) {
    int t = (tid >= off) ? tmp[tid - off] : 0;
    __syncthreads();
    tmp[tid] += t;
    __syncthreads();
  }
  if (tid < nb) blockSums[tid] = tmp[tid] - v;  // exclusive block offsets
}

__global__ __launch_bounds__(256) void k_scan3(const int* __restrict__ partial,
                                               const int* __restrict__ blockSums,
                                               int* __restrict__ rowptr,
                                               int* __restrict__ fill) {
  int i = blockIdx.x * 256 + threadIdx.x;
  if (i < N_NODES) {
    int v = partial[i] + blockSums[blockIdx.x];
    rowptr[i] = v;
    fill[i] = v;
  }
  if (i == 0) rowptr[N_NODES] = E_TOT;
}

__global__ __launch_bounds__(256) void k_scatter(const int* __restrict__ ei,
                                                 int* __restrict__ fill,
                                                 int* __restrict__ esrc) {
  int i = blockIdx.x * 256 + threadIdx.x;
  if (i >= E_TOT) return;
  int s, d;
  if (i < N_EDGES) { s = ei[i]; d = ei[N_EDGES + i]; }
  else             { s = i - N_EDGES; d = s; }
  int pos = atomicAdd(&fill[d], 1);
  esrc[pos] = s;
}

// ---------------- GEMM (X[N,K] @ W[K,256]) + attention-dot epilogue ----------------
// Block: 256 threads, 32 rows per block. Thread t owns column t for all 32 rows.
// Wave w (t in [64w,64w+63]) == head w; epilogue wave-reduces a_src/a_dst.

template <int K>
__global__ __launch_bounds__(256) void k_gemm_att(const float* __restrict__ X,
                                                  const float* __restrict__ W,
                                                  const float* __restrict__ att_s,
                                                  const float* __restrict__ att_d,
                                                  float* __restrict__ Hout,
                                                  float* __restrict__ asrc,
                                                  float* __restrict__ adst) {
  __shared__ float xs[32][K];
  const int tid = threadIdx.x;
  const int row0 = blockIdx.x * 32;

  // stage x tile (32 rows x K) via float4, coalesced
  const int nf4 = 32 * K / 4;
  for (int f = tid; f < nf4; f += 256) {
    int r = (4 * f) / K;
    int c = (4 * f) % K;
    *(float4*)&xs[r][c] = *(const float4*)&X[(size_t)(row0 + r) * K + c];
  }
  __syncthreads();

  float acc[32];
#pragma unroll
  for (int r = 0; r < 32; ++r) acc[r] = 0.f;

  for (int k = 0; k < K; k += 4) {
    float w0 = W[(size_t)(k + 0) * 256 + tid];
    float w1 = W[(size_t)(k + 1) * 256 + tid];
    float w2 = W[(size_t)(k + 2) * 256 + tid];
    float w3 = W[(size_t)(k + 3) * 256 + tid];
#pragma unroll
    for (int r = 0; r < 32; ++r) {
      float4 xv = *(const float4*)&xs[r][k];
      acc[r] = fmaf(xv.x, w0, acc[r]);
      acc[r] = fmaf(xv.y, w1, acc[r]);
      acc[r] = fmaf(xv.z, w2, acc[r]);
      acc[r] = fmaf(xv.w, w3, acc[r]);
    }
  }

  const int h = tid >> 6;     // head == wave index
  const int c = tid & 63;
  const float asv = att_s[h * 64 + c];
  const float adv = att_d[h * 64 + c];
#pragma unroll 4
  for (int r = 0; r < 32; ++r) {
    float v = acc[r];
    Hout[(size_t)(row0 + r) * 256 + tid] = v;
    float ps = v * asv;
    float pd = v * adv;
#pragma unroll
    for (int off = 32; off > 0; off >>= 1) {
      ps += __shfl_xor(ps, off);
      pd += __shfl_xor(pd, off);
    }
    if (c == 0) {
      asrc[(size_t)(row0 + r) * 4 + h] = ps;
      adst[(size_t)(row0 + r) * 4 + h] = pd;
    }
  }
}

// ---------------- Aggregation conv1: softmax over in-edges, weighted sum, +b1, PReLU ----------------
// One wave per dst node. Lane l owns float4 channels [4l..4l+3]; head = l>>4.

__global__ __launch_bounds__(256) void k_agg1(const float* __restrict__ h1,
                                              const float* __restrict__ asrc,
                                              const float* __restrict__ adst,
                                              const int* __restrict__ rowptr,
                                              const int* __restrict__ esrc,
                                              const float* __restrict__ b1,
                                              const float* __restrict__ prelu_a,
                                              float* __restrict__ outp) {
  int gid = blockIdx.x * 256 + threadIdx.x;
  int dst = gid >> 6;
  int lane = threadIdx.x & 63;
  if (dst >= N_NODES) return;
  int beg = rowptr[dst], end = rowptr[dst + 1];

  float ad[4];
#pragma unroll
  for (int h = 0; h < 4; ++h) ad[h] = adst[(size_t)dst * 4 + h];

  // phase A: per-head max and denom (lanes parallel over edges)
  float mh[4] = {-INFINITY, -INFINITY, -INFINITY, -INFINITY};
  for (int j = beg + lane; j < end; j += 64) {
    int s = esrc[j];
#pragma unroll
    for (int h = 0; h < 4; ++h) {
      float e = leaky(asrc[(size_t)s * 4 + h] + ad[h]);
      mh[h] = fmaxf(mh[h], e);
    }
  }
#pragma unroll
  for (int off = 1; off < 64; off <<= 1)
#pragma unroll
    for (int h = 0; h < 4; ++h) mh[h] = fmaxf(mh[h], __shfl_xor(mh[h], off));

  float dh[4] = {0.f, 0.f, 0.f, 0.f};
  for (int j = beg + lane; j < end; j += 64) {
    int s = esrc[j];
#pragma unroll
    for (int h = 0; h < 4; ++h) {
      float e = leaky(asrc[(size_t)s * 4 + h] + ad[h]);
      dh[h] += __expf(e - mh[h]);
    }
  }
#pragma unroll
  for (int off = 1; off < 64; off <<= 1)
#pragma unroll
    for (int h = 0; h < 4; ++h) dh[h] += __shfl_xor(dh[h], off);

  const int myh = lane >> 4;
  const float m_my = mh[myh];
  const float inv_my = 1.f / (dh[myh] + 1e-16f);
  const float ad_my = ad[myh];

  // phase B: weighted sum (all lanes per edge, coalesced float4)
  float4 acc = make_float4(0.f, 0.f, 0.f, 0.f);
  for (int j = beg; j < end; ++j) {
    int s = esrc[j];
    float alpha = __expf(leaky(asrc[(size_t)s * 4 + myh] + ad_my) - m_my) * inv_my;
    const float4 hv = *(const float4*)&h1[(size_t)s * 256 + 4 * lane];
    acc.x = fmaf(alpha, hv.x, acc.x);
    acc.y = fmaf(alpha, hv.y, acc.y);
    acc.z = fmaf(alpha, hv.z, acc.z);
    acc.w = fmaf(alpha, hv.w, acc.w);
  }

  const float a = prelu_a[0];
  const int c = 4 * lane;
  const float4 bv = *(const float4*)&b1[c];
  float4 r;
  r.x = acc.x + bv.x; r.x = r.x >= 0.f ? r.x : a * r.x;
  r.y = acc.y + bv.y; r.y = r.y >= 0.f ? r.y : a * r.y;
  r.z = acc.z + bv.z; r.z = r.z >= 0.f ? r.z : a * r.z;
  r.w = acc.w + bv.w; r.w = r.w >= 0.f ? r.w : a * r.w;
  *(float4*)&outp[(size_t)dst * 256 + c] = r;
}

// ---------------- Aggregation conv2: softmax, weighted sum, head-mean, +b2, PReLU, @Wl+bl ----------------

__global__ __launch_bounds__(256) void k_agg2(const float* __restrict__ h2,
                                              const float* __restrict__ asrc,
                                              const float* __restrict__ adst,
                                              const int* __restrict__ rowptr,
                                              const int* __restrict__ esrc,
                                              const float* __restrict__ b2,
                                              const float* __restrict__ prelu_a,
                                              const float* __restrict__ Wl,
                                              const float* __restrict__ bl,
                                              float* __restrict__ out) {
  int gid = blockIdx.x * 256 + threadIdx.x;
  int dst = gid >> 6;
  int lane = threadIdx.x & 63;
  if (dst >= N_NODES) return;
  int beg = rowptr[dst], end = rowptr[dst + 1];

  float ad[4];
#pragma unroll
  for (int h = 0; h < 4; ++h) ad[h] = adst[(size_t)dst * 4 + h];

  float mh[4] = {-INFINITY, -INFINITY, -INFINITY, -INFINITY};
  for (int j = beg + lane; j < end; j += 64) {
    int s = esrc[j];
#pragma unroll
    for (int h = 0; h < 4; ++h) {
      float e = leaky(asrc[(size_t)s * 4 + h] + ad[h]);
      mh[h] = fmaxf(mh[h], e);
    }
  }
#pragma unroll
  for (int off = 1; off < 64; off <<= 1)
#pragma unroll
    for (int h = 0; h < 4; ++h) mh[h] = fmaxf(mh[h], __shfl_xor(mh[h], off));

  float dh[4] = {0.f, 0.f, 0.f, 0.f};
  for (int j = beg + lane; j < end; j += 64) {
    int s = esrc[j];
#pragma unroll
    for (int h = 0; h < 4; ++h) {
      float e = leaky(asrc[(size_t)s * 4 + h] + ad[h]);
      dh[h] += __expf(e - mh[h]);
    }
  }
#pragma unroll
  for (int off = 1; off < 64; off <<= 1)
#pragma unroll
    for (int h = 0; h < 4; ++h) dh[h] += __shfl_xor(dh[h], off);

  const int myh = lane >> 4;
  const float m_my = mh[myh];
  const float inv_my = 1.f / (dh[myh] + 1e-16f);
  const float ad_my = ad[myh];

  float4 acc = make_float4(0.f, 0.f, 0.f, 0.f);
  for (int j = beg; j < end; ++j) {
    int s = esrc[j];
    float alpha = __expf(leaky(asrc[(size_t)s * 4 + myh] + ad_my) - m_my) * inv_my;
    const float4 hv = *(const float4*)&h2[(size_t)s * 256 + 4 * lane];
    acc.x = fmaf(alpha, hv.x, acc.x);
    acc.y = fmaf(alpha, hv.y, acc.y);
    acc.z = fmaf(alpha, hv.z, acc.z);
    acc.w = fmaf(alpha, hv.w, acc.w);
  }

  // head-mean: lanes {l, l+16, l+32, l+48} hold heads 0..3 for channel group 4*(l&15)
#pragma unroll
  for (int off = 16; off < 64; off <<= 1) {
    acc.x += __shfl_xor(acc.x, off);
    acc.y += __shfl_xor(acc.y, off);
    acc.z += __shfl_xor(acc.z, off);
    acc.w += __shfl_xor(acc.w, off);
  }

  const float a = prelu_a[0];
  const int c0 = 4 * (lane & 15);
  float4 v;
  v.x = 0.25f * acc.x + b2[c0 + 0]; v.x = v.x >= 0.f ? v.x : a * v.x;
  v.y = 0.25f * acc.y + b2[c0 + 1]; v.y = v.y >= 0.f ? v.y : a * v.y;
  v.z = 0.25f * acc.z + b2[c0 + 2]; v.z = v.z >= 0.f ? v.z : a * v.z;
  v.w = 0.25f * acc.w + b2[c0 + 3]; v.w = v.w >= 0.f ? v.w : a * v.w;

  float p = v.x * Wl[c0 + 0] + v.y * Wl[c0 + 1] + v.z * Wl[c0 + 2] + v.w * Wl[c0 + 3];
#pragma unroll
  for (int off = 1; off < 16; off <<= 1) p += __shfl_xor(p, off);

  if (lane == 0) out[dst] = p + bl[0];
}

// ---------------- launch ----------------

static inline int cdiv(int a, int b) { return (a + b - 1) / b; }

extern "C" void kernel_launch(void* const* d_in, const int* in_sizes, int n_in,
                              void* d_out, int out_size, void* d_ws, size_t ws_size,
                              hipStream_t stream) {
  const float* x   = (const float*)d_in[0];
  const int*   ei  = (const int*)d_in[1];
  const float* W1  = (const float*)d_in[2];
  const float* as1 = (const float*)d_in[3];
  const float* ad1 = (const float*)d_in[4];
  const float* b1  = (const float*)d_in[5];
  const float* W2  = (const float*)d_in[6];
  const float* as2 = (const float*)d_in[7];
  const float* ad2 = (const float*)d_in[8];
  const float* b2  = (const float*)d_in[9];
  const float* pa  = (const float*)d_in[10];
  const float* Wl  = (const float*)d_in[11];
  const float* bl  = (const float*)d_in[12];
  float* out = (float*)d_out;

  char* ws = (char*)d_ws;
  size_t off = 0;
  auto alloc = [&](size_t bytes) -> void* {
    void* p = ws + off;
    off += (bytes + 255) & ~(size_t)255;
    return p;
  };

  float* hbufA  = (float*)alloc((size_t)N_NODES * 256 * sizeof(float)); // h1, then h2
  float* hbufB  = (float*)alloc((size_t)N_NODES * 256 * sizeof(float)); // prelu(conv1 out)
  float* asrc1  = (float*)alloc((size_t)N_NODES * 4 * sizeof(float));
  float* adst1  = (float*)alloc((size_t)N_NODES * 4 * sizeof(float));
  float* asrc2  = (float*)alloc((size_t)N_NODES * 4 * sizeof(float));
  float* adst2  = (float*)alloc((size_t)N_NODES * 4 * sizeof(float));
  int*   counts = (int*)alloc((size_t)N_NODES * sizeof(int));
  int*   partial= (int*)alloc((size_t)N_NODES * sizeof(int));
  int*   rowptr = (int*)alloc((size_t)(N_NODES + 1) * sizeof(int));
  int*   fill   = (int*)alloc((size_t)N_NODES * sizeof(int));
  int*   esrc   = (int*)alloc((size_t)E_TOT * sizeof(int));
  int*   blockSums = (int*)alloc(2048 * sizeof(int));

  const int NB = cdiv(N_NODES, 256);   // 391 scan blocks

  // CSR build
  k_init_counts<<<NB, 256, 0, stream>>>(counts);
  k_hist<<<cdiv(N_EDGES, 256), 256, 0, stream>>>(ei, counts);
  k_scan1<<<NB, 256, 0, stream>>>(counts, partial, blockSums);
  k_scan2<<<1, 512, 0, stream>>>(blockSums, NB);
  k_scan3<<<NB, 256, 0, stream>>>(partial, blockSums, rowptr, fill);
  k_scatter<<<cdiv(E_TOT, 256), 256, 0, stream>>>(ei, fill, esrc);

  // conv1
  k_gemm_att<128><<<N_NODES / 32, 256, 0, stream>>>(x, W1, as1, ad1, hbufA, asrc1, adst1);
  k_agg1<<<N_NODES * 64 / 256, 256, 0, stream>>>(hbufA, asrc1, adst1, rowptr, esrc, b1, pa, hbufB);

  // conv2
  k_gemm_att<256><<<N_NODES / 32, 256, 0, stream>>>(hbufB, W2, as2, ad2, hbufA, asrc2, adst2);
  k_agg2<<<N_NODES * 64 / 256, 256, 0, stream>>>(hbufA, asrc2, adst2, rowptr, esrc, b2, pa, Wl, bl, out);
}

// Round 2
// 543.961 us; speedup vs baseline: 1.4852x; 1.4852x over previous
//
#include <hip/hip_runtime.h>
#include <cstdint>
#include <cstddef>

static constexpr int N_NODES = 100000;
static constexpr int N_EDGES = 600000;
static constexpr int E_TOT   = N_EDGES + N_NODES;
static constexpr float NEG_SLOPE = 0.2f;

typedef __attribute__((ext_vector_type(8))) short bf16x8;  // 8 bf16 (4 VGPR)
typedef __attribute__((ext_vector_type(4))) float f32x4;   // 4 fp32

__device__ __forceinline__ float leaky(float x) { return x >= 0.f ? x : NEG_SLOPE * x; }

__device__ __forceinline__ unsigned short f2bf(float f) {  // RNE truncate to bf16
  unsigned u = __float_as_uint(f);
  u = u + 0x7fffu + ((u >> 16) & 1u);
  return (unsigned short)(u >> 16);
}
__device__ __forceinline__ float bf2f(unsigned short h) {
  return __uint_as_float((unsigned)h << 16);
}

// ---------------- CSR build ----------------

__global__ __launch_bounds__(256) void k_init_counts(int* __restrict__ counts) {
  int i = blockIdx.x * 256 + threadIdx.x;
  if (i < N_NODES) counts[i] = 1;   // self-loop
}

__global__ __launch_bounds__(256) void k_hist(const int* __restrict__ ei, int* __restrict__ counts) {
  int e = blockIdx.x * 256 + threadIdx.x;
  if (e < N_EDGES) atomicAdd(&counts[ei[N_EDGES + e]], 1);
}

__global__ __launch_bounds__(256) void k_scan1(const int* __restrict__ counts,
                                               int* __restrict__ partial,
                                               int* __restrict__ blockSums) {
  __shared__ int tmp[256];
  int tid = threadIdx.x;
  int i = blockIdx.x * 256 + tid;
  int v = (i < N_NODES) ? counts[i] : 0;
  tmp[tid] = v;
  __syncthreads();
  for (int off = 1; off < 256; off <<= 1) {
    int t = (tid >= off) ? tmp[tid - off] : 0;
    __syncthreads();
    tmp[tid] += t;
    __syncthreads();
  }
  if (i < N_NODES) partial[i] = tmp[tid] - v;
  if (tid == 255) blockSums[blockIdx.x] = tmp[tid];
}

__global__ __launch_bounds__(512) void k_scan2(int* __restrict__ blockSums, int nb) {
  __shared__ int tmp[512];
  int tid = threadIdx.x;
  int v = (tid < nb) ? blockSums[tid] : 0;
  tmp[tid] = v;
  __syncthreads();
  for (int off = 1; off < 512; off <<= 1) {
    int t = (tid >= off) ? tmp[tid - off] : 0;
    __syncthreads();
    tmp[tid] += t;
    __syncthreads();
  }
  if (tid < nb) blockSums[tid] = tmp[tid] - v;
}

__global__ __launch_bounds__(256) void k_scan3(const int* __restrict__ partial,
                                               const int* __restrict__ blockSums,
                                               int* __restrict__ rowptr,
                                               int* __restrict__ fill) {
  int i = blockIdx.x * 256 + threadIdx.x;
  if (i < N_NODES) {
    int v = partial[i] + blockSums[blockIdx.x];
    rowptr[i] = v;
    fill[i] = v;
  }
  if (i == 0) rowptr[N_NODES] = E_TOT;
}

__global__ __launch_bounds__(256) void k_scatter(const int* __restrict__ ei,
                                                 int* __restrict__ fill,
                                                 int* __restrict__ esrc) {
  int i = blockIdx.x * 256 + threadIdx.x;
  if (i >= E_TOT) return;
  int s, d;
  if (i < N_EDGES) { s = ei[i]; d = ei[N_EDGES + i]; }
  else             { s = i - N_EDGES; d = s; }
  int pos = atomicAdd(&fill[d], 1);
  esrc[pos] = s;
}

// ---------------- weight prep ----------------
// Wt[c][k] = W[k][c] as bf16 hi/lo (B-fragment friendly layout).

template <int K>
__global__ __launch_bounds__(256) void k_wconv(const float* __restrict__ W,
                                               unsigned short* __restrict__ Wt_hi,
                                               unsigned short* __restrict__ Wt_lo) {
  int t = blockIdx.x * 256 + threadIdx.x;
  if (t >= K * 256) return;
  int k = t >> 8, c = t & 255;
  float v = W[t];
  unsigned short hi = f2bf(v);
  Wt_hi[(size_t)c * K + k] = hi;
  Wt_lo[(size_t)c * K + k] = f2bf(v - bf2f(hi));
}

// Wa[j][k] (j: 0..3 src-head, 4..7 dst-head, 8..15 zero pad), bf16 hi/lo.
// Wa[j][k] = sum_c W[k][h*64+c] * att[h][c]

template <int K>
__global__ __launch_bounds__(256) void k_wa(const float* __restrict__ W,
                                            const float* __restrict__ att_s,
                                            const float* __restrict__ att_d,
                                            unsigned short* __restrict__ Wat_hi,
                                            unsigned short* __restrict__ Wat_lo) {
  int k = blockIdx.x;
  int h = threadIdx.x >> 6, c = threadIdx.x & 63;
  float wv = W[(size_t)k * 256 + h * 64 + c];
  float ps = wv * att_s[h * 64 + c];
  float pd = wv * att_d[h * 64 + c];
#pragma unroll
  for (int off = 32; off > 0; off >>= 1) {
    ps += __shfl_xor(ps, off);
    pd += __shfl_xor(pd, off);
  }
  if (c == 0) {
    unsigned short hi = f2bf(ps);
    Wat_hi[(size_t)h * K + k] = hi;
    Wat_lo[(size_t)h * K + k] = f2bf(ps - bf2f(hi));
    hi = f2bf(pd);
    Wat_hi[(size_t)(4 + h) * K + k] = hi;
    Wat_lo[(size_t)(4 + h) * K + k] = f2bf(pd - bf2f(hi));
  }
  if (threadIdx.x >= 8 && threadIdx.x < 16) {   // zero rows 8..15
    Wat_hi[(size_t)threadIdx.x * K + k] = 0;
    Wat_lo[(size_t)threadIdx.x * K + k] = 0;
  }
}

// ---------------- x -> bf16 hi/lo ----------------

__global__ __launch_bounds__(256) void k_conv_x(const float* __restrict__ X,
                                                unsigned short* __restrict__ Xhi,
                                                unsigned short* __restrict__ Xlo) {
  size_t t = (size_t)blockIdx.x * 256 + threadIdx.x;  // handles 4 floats
  float4 v = *(const float4*)&X[t * 4];
  ushort4 hi, lo;
  hi.x = f2bf(v.x); lo.x = f2bf(v.x - bf2f(hi.x));
  hi.y = f2bf(v.y); lo.y = f2bf(v.y - bf2f(hi.y));
  hi.z = f2bf(v.z); lo.z = f2bf(v.z - bf2f(hi.z));
  hi.w = f2bf(v.w); lo.w = f2bf(v.w - bf2f(hi.w));
  *(ushort4*)&Xhi[t * 4] = hi;
  *(ushort4*)&Xlo[t * 4] = lo;
}

// ---------------- MFMA GEMM: H[N,256] = A[N,K] @ W[K,256], split bf16 hi/lo ----------------
// Block: 256 thr = 4 waves. Block tile 64 rows x 256 cols; wave w owns cols 64w..64w+63
// (4 col-tiles of 16), 4 row-tiles of 16. 3-product split: Ah*Bh + Al*Bh + Ah*Bl.
// Wave 0 additionally computes the attention-dot tile (8 cols of Wa) -> asrc/adst.

template <int K>
__global__ __launch_bounds__(256) void k_gemm_mfma(
    const unsigned short* __restrict__ Ahi, const unsigned short* __restrict__ Alo,
    const unsigned short* __restrict__ Bhi, const unsigned short* __restrict__ Blo,
    const unsigned short* __restrict__ Whi, const unsigned short* __restrict__ Wlo,
    float* __restrict__ H, float* __restrict__ asrc, float* __restrict__ adst) {
  const int tid = threadIdx.x;
  const int w = tid >> 6, lane = tid & 63;
  const int lhi = lane >> 4, llo = lane & 15;
  const int wrow = blockIdx.x * 64;
  const int wcol = w * 64;

  f32x4 acc[4][4] = {};
  f32x4 acca[4] = {};

  size_t arow[4];
#pragma unroll
  for (int rt = 0; rt < 4; ++rt) {
    int r = wrow + rt * 16 + llo;
    if (r > N_NODES - 1) r = N_NODES - 1;
    arow[rt] = (size_t)r * K + lhi * 8;
  }
  size_t brow[4];
#pragma unroll
  for (int ct = 0; ct < 4; ++ct)
    brow[ct] = (size_t)(wcol + ct * 16 + llo) * K + lhi * 8;
  const size_t watrow = (size_t)llo * K + lhi * 8;

  for (int kc = 0; kc < K; kc += 32) {
    bf16x8 ah[4], al[4];
#pragma unroll
    for (int rt = 0; rt < 4; ++rt) {
      ah[rt] = *(const bf16x8*)&Ahi[arow[rt] + kc];
      al[rt] = *(const bf16x8*)&Alo[arow[rt] + kc];
    }
#pragma unroll
    for (int ct = 0; ct < 4; ++ct) {
      bf16x8 bh = *(const bf16x8*)&Bhi[brow[ct] + kc];
      bf16x8 bl = *(const bf16x8*)&Blo[brow[ct] + kc];
#pragma unroll
      for (int rt = 0; rt < 4; ++rt) {
        acc[rt][ct] = __builtin_amdgcn_mfma_f32_16x16x32_bf16(ah[rt], bh, acc[rt][ct], 0, 0, 0);
        acc[rt][ct] = __builtin_amdgcn_mfma_f32_16x16x32_bf16(al[rt], bh, acc[rt][ct], 0, 0, 0);
        acc[rt][ct] = __builtin_amdgcn_mfma_f32_16x16x32_bf16(ah[rt], bl, acc[rt][ct], 0, 0, 0);
      }
    }
    if (w == 0) {
      bf16x8 bh = *(const bf16x8*)&Whi[watrow + kc];
      bf16x8 bl = *(const bf16x8*)&Wlo[watrow + kc];
#pragma unroll
      for (int rt = 0; rt < 4; ++rt) {
        acca[rt] = __builtin_amdgcn_mfma_f32_16x16x32_bf16(ah[rt], bh, acca[rt], 0, 0, 0);
        acca[rt] = __builtin_amdgcn_mfma_f32_16x16x32_bf16(al[rt], bh, acca[rt], 0, 0, 0);
        acca[rt] = __builtin_amdgcn_mfma_f32_16x16x32_bf16(ah[rt], bl, acca[rt], 0, 0, 0);
      }
    }
  }

  // C/D layout: col = lane&15, row = (lane>>4)*4 + reg
#pragma unroll
  for (int rt = 0; rt < 4; ++rt) {
    const int r0 = wrow + rt * 16 + lhi * 4;
#pragma unroll
    for (int ct = 0; ct < 4; ++ct) {
      const int cc = wcol + ct * 16 + llo;
#pragma unroll
      for (int e = 0; e < 4; ++e) {
        int r = r0 + e;
        if (r < N_NODES) H[(size_t)r * 256 + cc] = acc[rt][ct][e];
      }
    }
    if (w == 0 && llo < 8) {
#pragma unroll
      for (int e = 0; e < 4; ++e) {
        int r = r0 + e;
        if (r < N_NODES) {
          float v = acca[rt][e];
          if (llo < 4) asrc[(size_t)r * 4 + llo] = v;
          else         adst[(size_t)r * 4 + (llo - 4)] = v;
        }
      }
    }
  }
}

// ---------------- Aggregation conv1: softmax, weighted sum, +b1, PReLU, -> bf16 hi/lo ----------------

__global__ __launch_bounds__(256) void k_agg1(const float* __restrict__ h1,
                                              const float* __restrict__ asrc,
                                              const float* __restrict__ adst,
                                              const int* __restrict__ rowptr,
                                              const int* __restrict__ esrc,
                                              const float* __restrict__ b1,
                                              const float* __restrict__ prelu_a,
                                              unsigned short* __restrict__ out_hi,
                                              unsigned short* __restrict__ out_lo) {
  int gid = blockIdx.x * 256 + threadIdx.x;
  int dst = gid >> 6;
  int lane = threadIdx.x & 63;
  if (dst >= N_NODES) return;
  int beg = rowptr[dst], end = rowptr[dst + 1];

  float ad[4];
#pragma unroll
  for (int h = 0; h < 4; ++h) ad[h] = adst[(size_t)dst * 4 + h];

  float mh[4] = {-INFINITY, -INFINITY, -INFINITY, -INFINITY};
  for (int j = beg + lane; j < end; j += 64) {
    int s = esrc[j];
#pragma unroll
    for (int h = 0; h < 4; ++h) {
      float e = leaky(asrc[(size_t)s * 4 + h] + ad[h]);
      mh[h] = fmaxf(mh[h], e);
    }
  }
#pragma unroll
  for (int off = 1; off < 64; off <<= 1)
#pragma unroll
    for (int h = 0; h < 4; ++h) mh[h] = fmaxf(mh[h], __shfl_xor(mh[h], off));

  float dh[4] = {0.f, 0.f, 0.f, 0.f};
  for (int j = beg + lane; j < end; j += 64) {
    int s = esrc[j];
#pragma unroll
    for (int h = 0; h < 4; ++h) {
      float e = leaky(asrc[(size_t)s * 4 + h] + ad[h]);
      dh[h] += __expf(e - mh[h]);
    }
  }
#pragma unroll
  for (int off = 1; off < 64; off <<= 1)
#pragma unroll
    for (int h = 0; h < 4; ++h) dh[h] += __shfl_xor(dh[h], off);

  const int myh = lane >> 4;
  const float m_my = mh[myh];
  const float inv_my = 1.f / (dh[myh] + 1e-16f);
  const float ad_my = ad[myh];

  float4 acc = make_float4(0.f, 0.f, 0.f, 0.f);
  for (int j = beg; j < end; ++j) {
    int s = esrc[j];
    float alpha = __expf(leaky(asrc[(size_t)s * 4 + myh] + ad_my) - m_my) * inv_my;
    const float4 hv = *(const float4*)&h1[(size_t)s * 256 + 4 * lane];
    acc.x = fmaf(alpha, hv.x, acc.x);
    acc.y = fmaf(alpha, hv.y, acc.y);
    acc.z = fmaf(alpha, hv.z, acc.z);
    acc.w = fmaf(alpha, hv.w, acc.w);
  }

  const float a = prelu_a[0];
  const int c = 4 * lane;
  const float4 bv = *(const float4*)&b1[c];
  float4 r;
  r.x = acc.x + bv.x; r.x = r.x >= 0.f ? r.x : a * r.x;
  r.y = acc.y + bv.y; r.y = r.y >= 0.f ? r.y : a * r.y;
  r.z = acc.z + bv.z; r.z = r.z >= 0.f ? r.z : a * r.z;
  r.w = acc.w + bv.w; r.w = r.w >= 0.f ? r.w : a * r.w;

  ushort4 hi, lo;
  hi.x = f2bf(r.x); lo.x = f2bf(r.x - bf2f(hi.x));
  hi.y = f2bf(r.y); lo.y = f2bf(r.y - bf2f(hi.y));
  hi.z = f2bf(r.z); lo.z = f2bf(r.z - bf2f(hi.z));
  hi.w = f2bf(r.w); lo.w = f2bf(r.w - bf2f(hi.w));
  *(ushort4*)&out_hi[(size_t)dst * 256 + c] = hi;
  *(ushort4*)&out_lo[(size_t)dst * 256 + c] = lo;
}

// ---------------- Aggregation conv2: softmax, weighted sum, head-mean, +b2, PReLU, @Wl+bl ----------------

__global__ __launch_bounds__(256) void k_agg2(const float* __restrict__ h2,
                                              const float* __restrict__ asrc,
                                              const float* __restrict__ adst,
                                              const int* __restrict__ rowptr,
                                              const int* __restrict__ esrc,
                                              const float* __restrict__ b2,
                                              const float* __restrict__ prelu_a,
                                              const float* __restrict__ Wl,
                                              const float* __restrict__ bl,
                                              float* __restrict__ out) {
  int gid = blockIdx.x * 256 + threadIdx.x;
  int dst = gid >> 6;
  int lane = threadIdx.x & 63;
  if (dst >= N_NODES) return;
  int beg = rowptr[dst], end = rowptr[dst + 1];

  float ad[4];
#pragma unroll
  for (int h = 0; h < 4; ++h) ad[h] = adst[(size_t)dst * 4 + h];

  float mh[4] = {-INFINITY, -INFINITY, -INFINITY, -INFINITY};
  for (int j = beg + lane; j < end; j += 64) {
    int s = esrc[j];
#pragma unroll
    for (int h = 0; h < 4; ++h) {
      float e = leaky(asrc[(size_t)s * 4 + h] + ad[h]);
      mh[h] = fmaxf(mh[h], e);
    }
  }
#pragma unroll
  for (int off = 1; off < 64; off <<= 1)
#pragma unroll
    for (int h = 0; h < 4; ++h) mh[h] = fmaxf(mh[h], __shfl_xor(mh[h], off));

  float dh[4] = {0.f, 0.f, 0.f, 0.f};
  for (int j = beg + lane; j < end; j += 64) {
    int s = esrc[j];
#pragma unroll
    for (int h = 0; h < 4; ++h) {
      float e = leaky(asrc[(size_t)s * 4 + h] + ad[h]);
      dh[h] += __expf(e - mh[h]);
    }
  }
#pragma unroll
  for (int off = 1; off < 64; off <<= 1)
#pragma unroll
    for (int h = 0; h < 4; ++h) dh[h] += __shfl_xor(dh[h], off);

  const int myh = lane >> 4;
  const float m_my = mh[myh];
  const float inv_my = 1.f / (dh[myh] + 1e-16f);
  const float ad_my = ad[myh];

  float4 acc = make_float4(0.f, 0.f, 0.f, 0.f);
  for (int j = beg; j < end; ++j) {
    int s = esrc[j];
    float alpha = __expf(leaky(asrc[(size_t)s * 4 + myh] + ad_my) - m_my) * inv_my;
    const float4 hv = *(const float4*)&h2[(size_t)s * 256 + 4 * lane];
    acc.x = fmaf(alpha, hv.x, acc.x);
    acc.y = fmaf(alpha, hv.y, acc.y);
    acc.z = fmaf(alpha, hv.z, acc.z);
    acc.w = fmaf(alpha, hv.w, acc.w);
  }

#pragma unroll
  for (int off = 16; off < 64; off <<= 1) {
    acc.x += __shfl_xor(acc.x, off);
    acc.y += __shfl_xor(acc.y, off);
    acc.z += __shfl_xor(acc.z, off);
    acc.w += __shfl_xor(acc.w, off);
  }

  const float a = prelu_a[0];
  const int c0 = 4 * (lane & 15);
  float4 v;
  v.x = 0.25f * acc.x + b2[c0 + 0]; v.x = v.x >= 0.f ? v.x : a * v.x;
  v.y = 0.25f * acc.y + b2[c0 + 1]; v.y = v.y >= 0.f ? v.y : a * v.y;
  v.z = 0.25f * acc.z + b2[c0 + 2]; v.z = v.z >= 0.f ? v.z : a * v.z;
  v.w = 0.25f * acc.w + b2[c0 + 3]; v.w = v.w >= 0.f ? v.w : a * v.w;

  float p = v.x * Wl[c0 + 0] + v.y * Wl[c0 + 1] + v.z * Wl[c0 + 2] + v.w * Wl[c0 + 3];
#pragma unroll
  for (int off = 1; off < 16; off <<= 1) p += __shfl_xor(p, off);

  if (lane == 0) out[dst] = p + bl[0];
}

// ---------------- launch ----------------

static inline int cdiv(int a, int b) { return (a + b - 1) / b; }

extern "C" void kernel_launch(void* const* d_in, const int* in_sizes, int n_in,
                              void* d_out, int out_size, void* d_ws, size_t ws_size,
                              hipStream_t stream) {
  const float* x   = (const float*)d_in[0];
  const int*   ei  = (const int*)d_in[1];
  const float* W1  = (const float*)d_in[2];
  const float* as1 = (const float*)d_in[3];
  const float* ad1 = (const float*)d_in[4];
  const float* b1  = (const float*)d_in[5];
  const float* W2  = (const float*)d_in[6];
  const float* as2 = (const float*)d_in[7];
  const float* ad2 = (const float*)d_in[8];
  const float* b2  = (const float*)d_in[9];
  const float* pa  = (const float*)d_in[10];
  const float* Wl  = (const float*)d_in[11];
  const float* bl  = (const float*)d_in[12];
  float* out = (float*)d_out;

  char* ws = (char*)d_ws;
  size_t off = 0;
  auto alloc = [&](size_t bytes) -> void* {
    void* p = ws + off;
    off += (bytes + 255) & ~(size_t)255;
    return p;
  };

  float* hbufA = (float*)alloc((size_t)N_NODES * 256 * sizeof(float));    // h1, then h2 (fp32)
  // R1: x_hi/x_lo live here during conv1; h1p_hi/h1p_lo overwrite after agg1
  unsigned short* R1 = (unsigned short*)alloc((size_t)N_NODES * 256 * 2 * sizeof(unsigned short));
  unsigned short* x_hi   = R1;                                // [N][128]
  unsigned short* x_lo   = R1 + (size_t)N_NODES * 128;
  unsigned short* h1p_hi = R1;                                // [N][256]
  unsigned short* h1p_lo = R1 + (size_t)N_NODES * 256;

  float* asrc1 = (float*)alloc((size_t)N_NODES * 4 * sizeof(float));
  float* adst1 = (float*)alloc((size_t)N_NODES * 4 * sizeof(float));
  float* asrc2 = (float*)alloc((size_t)N_NODES * 4 * sizeof(float));
  float* adst2 = (float*)alloc((size_t)N_NODES * 4 * sizeof(float));

  unsigned short* Wt1_hi  = (unsigned short*)alloc(256 * 128 * sizeof(unsigned short));
  unsigned short* Wt1_lo  = (unsigned short*)alloc(256 * 128 * sizeof(unsigned short));
  unsigned short* Wat1_hi = (unsigned short*)alloc(16 * 128 * sizeof(unsigned short));
  unsigned short* Wat1_lo = (unsigned short*)alloc(16 * 128 * sizeof(unsigned short));
  unsigned short* Wt2_hi  = (unsigned short*)alloc(256 * 256 * sizeof(unsigned short));
  unsigned short* Wt2_lo  = (unsigned short*)alloc(256 * 256 * sizeof(unsigned short));
  unsigned short* Wat2_hi = (unsigned short*)alloc(16 * 256 * sizeof(unsigned short));
  unsigned short* Wat2_lo = (unsigned short*)alloc(16 * 256 * sizeof(unsigned short));

  int* counts  = (int*)alloc((size_t)N_NODES * sizeof(int));
  int* partial = (int*)alloc((size_t)N_NODES * sizeof(int));
  int* rowptr  = (int*)alloc((size_t)(N_NODES + 1) * sizeof(int));
  int* fill    = (int*)alloc((size_t)N_NODES * sizeof(int));
  int* esrc    = (int*)alloc((size_t)E_TOT * sizeof(int));
  int* blockSums = (int*)alloc(2048 * sizeof(int));

  const int NB = cdiv(N_NODES, 256);

  // CSR build
  k_init_counts<<<NB, 256, 0, stream>>>(counts);
  k_hist<<<cdiv(N_EDGES, 256), 256, 0, stream>>>(ei, counts);
  k_scan1<<<NB, 256, 0, stream>>>(counts, partial, blockSums);
  k_scan2<<<1, 512, 0, stream>>>(blockSums, NB);
  k_scan3<<<NB, 256, 0, stream>>>(partial, blockSums, rowptr, fill);
  k_scatter<<<cdiv(E_TOT, 256), 256, 0, stream>>>(ei, fill, esrc);

  // weight prep
  k_wconv<128><<<cdiv(128 * 256, 256), 256, 0, stream>>>(W1, Wt1_hi, Wt1_lo);
  k_wa<128><<<128, 256, 0, stream>>>(W1, as1, ad1, Wat1_hi, Wat1_lo);
  k_wconv<256><<<cdiv(256 * 256, 256), 256, 0, stream>>>(W2, Wt2_hi, Wt2_lo);
  k_wa<256><<<256, 256, 0, stream>>>(W2, as2, ad2, Wat2_hi, Wat2_lo);

  // x -> bf16 hi/lo
  k_conv_x<<<N_NODES * 128 / 4 / 256, 256, 0, stream>>>(x, x_hi, x_lo);

  const int GEMM_GRID = cdiv(N_NODES, 64);  // 1563

  // conv1
  k_gemm_mfma<128><<<GEMM_GRID, 256, 0, stream>>>(x_hi, x_lo, Wt1_hi, Wt1_lo,
                                                  Wat1_hi, Wat1_lo, hbufA, asrc1, adst1);
  k_agg1<<<N_NODES * 64 / 256, 256, 0, stream>>>(hbufA, asrc1, adst1, rowptr, esrc,
                                                 b1, pa, h1p_hi, h1p_lo);

  // conv2
  k_gemm_mfma<256><<<GEMM_GRID, 256, 0, stream>>>(h1p_hi, h1p_lo, Wt2_hi, Wt2_lo,
                                                  Wat2_hi, Wat2_lo, hbufA, asrc2, adst2);
  k_agg2<<<N_NODES * 64 / 256, 256, 0, stream>>>(hbufA, asrc2, adst2, rowptr, esrc,
                                                 b2, pa, Wl, bl, out);
}

// Round 3
// 529.669 us; speedup vs baseline: 1.5252x; 1.0270x over previous
//
#include <hip/hip_runtime.h>
#include <cstdint>
#include <cstddef>

static constexpr int N_NODES = 100000;
static constexpr int N_EDGES = 600000;
static constexpr int E_TOT   = N_EDGES + N_NODES;
static constexpr float NEG_SLOPE = 0.2f;

typedef __attribute__((ext_vector_type(8))) short bf16x8;   // 8 bf16 (4 VGPR)
typedef __attribute__((ext_vector_type(4))) float f32x4;    // 4 fp32
typedef __attribute__((ext_vector_type(4))) _Float16 half4; // 4 fp16 (8B)

__device__ __forceinline__ float leaky(float x) { return x >= 0.f ? x : NEG_SLOPE * x; }

__device__ __forceinline__ unsigned short f2bf(float f) {  // RNE to bf16
  unsigned u = __float_as_uint(f);
  u = u + 0x7fffu + ((u >> 16) & 1u);
  return (unsigned short)(u >> 16);
}
__device__ __forceinline__ float bf2f(unsigned short h) {
  return __uint_as_float((unsigned)h << 16);
}

// ---------------- CSR build ----------------

__global__ __launch_bounds__(256) void k_init_counts(int* __restrict__ counts) {
  int i = blockIdx.x * 256 + threadIdx.x;
  if (i < N_NODES) counts[i] = 1;   // self-loop
}

__global__ __launch_bounds__(256) void k_hist(const int* __restrict__ ei, int* __restrict__ counts) {
  int e = blockIdx.x * 256 + threadIdx.x;
  if (e < N_EDGES) atomicAdd(&counts[ei[N_EDGES + e]], 1);
}

__global__ __launch_bounds__(256) void k_scan1(const int* __restrict__ counts,
                                               int* __restrict__ partial,
                                               int* __restrict__ blockSums) {
  __shared__ int tmp[256];
  int tid = threadIdx.x;
  int i = blockIdx.x * 256 + tid;
  int v = (i < N_NODES) ? counts[i] : 0;
  tmp[tid] = v;
  __syncthreads();
  for (int off = 1; off < 256; off <<= 1) {
    int t = (tid >= off) ? tmp[tid - off] : 0;
    __syncthreads();
    tmp[tid] += t;
    __syncthreads();
  }
  if (i < N_NODES) partial[i] = tmp[tid] - v;
  if (tid == 255) blockSums[blockIdx.x] = tmp[tid];
}

__global__ __launch_bounds__(512) void k_scan2(int* __restrict__ blockSums, int nb) {
  __shared__ int tmp[512];
  int tid = threadIdx.x;
  int v = (tid < nb) ? blockSums[tid] : 0;
  tmp[tid] = v;
  __syncthreads();
  for (int off = 1; off < 512; off <<= 1) {
    int t = (tid >= off) ? tmp[tid - off] : 0;
    __syncthreads();
    tmp[tid] += t;
    __syncthreads();
  }
  if (tid < nb) blockSums[tid] = tmp[tid] - v;
}

__global__ __launch_bounds__(256) void k_scan3(const int* __restrict__ partial,
                                               const int* __restrict__ blockSums,
                                               int* __restrict__ rowptr,
                                               int* __restrict__ fill) {
  int i = blockIdx.x * 256 + threadIdx.x;
  if (i < N_NODES) {
    int v = partial[i] + blockSums[blockIdx.x];
    rowptr[i] = v;
    fill[i] = v;
  }
  if (i == 0) rowptr[N_NODES] = E_TOT;
}

__global__ __launch_bounds__(256) void k_scatter(const int* __restrict__ ei,
                                                 int* __restrict__ fill,
                                                 int* __restrict__ esrc) {
  int i = blockIdx.x * 256 + threadIdx.x;
  if (i >= E_TOT) return;
  int s, d;
  if (i < N_EDGES) { s = ei[i]; d = ei[N_EDGES + i]; }
  else             { s = i - N_EDGES; d = s; }
  int pos = atomicAdd(&fill[d], 1);
  esrc[pos] = s;
}

// ---------------- weight prep ----------------

template <int K>
__global__ __launch_bounds__(256) void k_wconv(const float* __restrict__ W,
                                               unsigned short* __restrict__ Wt_hi,
                                               unsigned short* __restrict__ Wt_lo) {
  int t = blockIdx.x * 256 + threadIdx.x;
  if (t >= K * 256) return;
  int k = t >> 8, c = t & 255;
  float v = W[t];
  unsigned short hi = f2bf(v);
  Wt_hi[(size_t)c * K + k] = hi;
  Wt_lo[(size_t)c * K + k] = f2bf(v - bf2f(hi));
}

template <int K>
__global__ __launch_bounds__(256) void k_wa(const float* __restrict__ W,
                                            const float* __restrict__ att_s,
                                            const float* __restrict__ att_d,
                                            unsigned short* __restrict__ Wat_hi,
                                            unsigned short* __restrict__ Wat_lo) {
  int k = blockIdx.x;
  int h = threadIdx.x >> 6, c = threadIdx.x & 63;
  float wv = W[(size_t)k * 256 + h * 64 + c];
  float ps = wv * att_s[h * 64 + c];
  float pd = wv * att_d[h * 64 + c];
#pragma unroll
  for (int off = 32; off > 0; off >>= 1) {
    ps += __shfl_xor(ps, off);
    pd += __shfl_xor(pd, off);
  }
  if (c == 0) {
    unsigned short hi = f2bf(ps);
    Wat_hi[(size_t)h * K + k] = hi;
    Wat_lo[(size_t)h * K + k] = f2bf(ps - bf2f(hi));
    hi = f2bf(pd);
    Wat_hi[(size_t)(4 + h) * K + k] = hi;
    Wat_lo[(size_t)(4 + h) * K + k] = f2bf(pd - bf2f(hi));
  }
  if (threadIdx.x >= 8 && threadIdx.x < 16) {
    Wat_hi[(size_t)threadIdx.x * K + k] = 0;
    Wat_lo[(size_t)threadIdx.x * K + k] = 0;
  }
}

// ---------------- x -> bf16 hi/lo ----------------

__global__ __launch_bounds__(256) void k_conv_x(const float* __restrict__ X,
                                                unsigned short* __restrict__ Xhi,
                                                unsigned short* __restrict__ Xlo) {
  size_t t = (size_t)blockIdx.x * 256 + threadIdx.x;  // handles 4 floats
  float4 v = *(const float4*)&X[t * 4];
  ushort4 hi, lo;
  hi.x = f2bf(v.x); lo.x = f2bf(v.x - bf2f(hi.x));
  hi.y = f2bf(v.y); lo.y = f2bf(v.y - bf2f(hi.y));
  hi.z = f2bf(v.z); lo.z = f2bf(v.z - bf2f(hi.z));
  hi.w = f2bf(v.w); lo.w = f2bf(v.w - bf2f(hi.w));
  *(ushort4*)&Xhi[t * 4] = hi;
  *(ushort4*)&Xlo[t * 4] = lo;
}

// ---------------- MFMA GEMM: H[N,256] = A[N,K] @ W[K,256], split bf16 hi/lo ----------------
// Output H written as fp16 (gather table). Wave 0 computes attention dots via Wa tile.

template <int K>
__global__ __launch_bounds__(256) void k_gemm_mfma(
    const unsigned short* __restrict__ Ahi, const unsigned short* __restrict__ Alo,
    const unsigned short* __restrict__ Bhi, const unsigned short* __restrict__ Blo,
    const unsigned short* __restrict__ Whi, const unsigned short* __restrict__ Wlo,
    _Float16* __restrict__ H, float* __restrict__ asrc, float* __restrict__ adst) {
  const int tid = threadIdx.x;
  const int w = tid >> 6, lane = tid & 63;
  const int lhi = lane >> 4, llo = lane & 15;
  const int wrow = blockIdx.x * 64;
  const int wcol = w * 64;

  f32x4 acc[4][4] = {};
  f32x4 acca[4] = {};

  size_t arow[4];
#pragma unroll
  for (int rt = 0; rt < 4; ++rt) {
    int r = wrow + rt * 16 + llo;
    if (r > N_NODES - 1) r = N_NODES - 1;
    arow[rt] = (size_t)r * K + lhi * 8;
  }
  size_t brow[4];
#pragma unroll
  for (int ct = 0; ct < 4; ++ct)
    brow[ct] = (size_t)(wcol + ct * 16 + llo) * K + lhi * 8;
  const size_t watrow = (size_t)llo * K + lhi * 8;

  for (int kc = 0; kc < K; kc += 32) {
    bf16x8 ah[4], al[4];
#pragma unroll
    for (int rt = 0; rt < 4; ++rt) {
      ah[rt] = *(const bf16x8*)&Ahi[arow[rt] + kc];
      al[rt] = *(const bf16x8*)&Alo[arow[rt] + kc];
    }
#pragma unroll
    for (int ct = 0; ct < 4; ++ct) {
      bf16x8 bh = *(const bf16x8*)&Bhi[brow[ct] + kc];
      bf16x8 bl = *(const bf16x8*)&Blo[brow[ct] + kc];
#pragma unroll
      for (int rt = 0; rt < 4; ++rt) {
        acc[rt][ct] = __builtin_amdgcn_mfma_f32_16x16x32_bf16(ah[rt], bh, acc[rt][ct], 0, 0, 0);
        acc[rt][ct] = __builtin_amdgcn_mfma_f32_16x16x32_bf16(al[rt], bh, acc[rt][ct], 0, 0, 0);
        acc[rt][ct] = __builtin_amdgcn_mfma_f32_16x16x32_bf16(ah[rt], bl, acc[rt][ct], 0, 0, 0);
      }
    }
    if (w == 0) {
      bf16x8 bh = *(const bf16x8*)&Whi[watrow + kc];
      bf16x8 bl = *(const bf16x8*)&Wlo[watrow + kc];
#pragma unroll
      for (int rt = 0; rt < 4; ++rt) {
        acca[rt] = __builtin_amdgcn_mfma_f32_16x16x32_bf16(ah[rt], bh, acca[rt], 0, 0, 0);
        acca[rt] = __builtin_amdgcn_mfma_f32_16x16x32_bf16(al[rt], bh, acca[rt], 0, 0, 0);
        acca[rt] = __builtin_amdgcn_mfma_f32_16x16x32_bf16(ah[rt], bl, acca[rt], 0, 0, 0);
      }
    }
  }

  // C/D layout: col = lane&15, row = (lane>>4)*4 + reg
#pragma unroll
  for (int rt = 0; rt < 4; ++rt) {
    const int r0 = wrow + rt * 16 + lhi * 4;
#pragma unroll
    for (int ct = 0; ct < 4; ++ct) {
      const int cc = wcol + ct * 16 + llo;
#pragma unroll
      for (int e = 0; e < 4; ++e) {
        int r = r0 + e;
        if (r < N_NODES) H[(size_t)r * 256 + cc] = (_Float16)acc[rt][ct][e];
      }
    }
    if (w == 0 && llo < 8) {
#pragma unroll
      for (int e = 0; e < 4; ++e) {
        int r = r0 + e;
        if (r < N_NODES) {
          float v = acca[rt][e];
          if (llo < 4) asrc[(size_t)r * 4 + llo] = v;
          else         adst[(size_t)r * 4 + (llo - 4)] = v;
        }
      }
    }
  }
}

// ---------------- Aggregation conv1: softmax, weighted sum (fp16 gather), +b1, PReLU, -> bf16 hi/lo ----------------

__global__ __launch_bounds__(256) void k_agg1(const _Float16* __restrict__ h1,
                                              const float* __restrict__ asrc,
                                              const float* __restrict__ adst,
                                              const int* __restrict__ rowptr,
                                              const int* __restrict__ esrc,
                                              const float* __restrict__ b1,
                                              const float* __restrict__ prelu_a,
                                              unsigned short* __restrict__ out_hi,
                                              unsigned short* __restrict__ out_lo) {
  int gid = blockIdx.x * 256 + threadIdx.x;
  int dst = gid >> 6;
  int lane = threadIdx.x & 63;
  if (dst >= N_NODES) return;
  int beg = rowptr[dst], end = rowptr[dst + 1];

  float ad[4];
#pragma unroll
  for (int h = 0; h < 4; ++h) ad[h] = adst[(size_t)dst * 4 + h];

  float mh[4] = {-INFINITY, -INFINITY, -INFINITY, -INFINITY};
  for (int j = beg + lane; j < end; j += 64) {
    int s = esrc[j];
#pragma unroll
    for (int h = 0; h < 4; ++h) {
      float e = leaky(asrc[(size_t)s * 4 + h] + ad[h]);
      mh[h] = fmaxf(mh[h], e);
    }
  }
#pragma unroll
  for (int off = 1; off < 64; off <<= 1)
#pragma unroll
    for (int h = 0; h < 4; ++h) mh[h] = fmaxf(mh[h], __shfl_xor(mh[h], off));

  float dh[4] = {0.f, 0.f, 0.f, 0.f};
  for (int j = beg + lane; j < end; j += 64) {
    int s = esrc[j];
#pragma unroll
    for (int h = 0; h < 4; ++h) {
      float e = leaky(asrc[(size_t)s * 4 + h] + ad[h]);
      dh[h] += __expf(e - mh[h]);
    }
  }
#pragma unroll
  for (int off = 1; off < 64; off <<= 1)
#pragma unroll
    for (int h = 0; h < 4; ++h) dh[h] += __shfl_xor(dh[h], off);

  const int myh = lane >> 4;
  const float m_my = mh[myh];
  const float inv_my = 1.f / (dh[myh] + 1e-16f);
  const float ad_my = ad[myh];

  float4 acc = make_float4(0.f, 0.f, 0.f, 0.f);
  for (int j = beg; j < end; ++j) {
    int s = esrc[j];
    float alpha = __expf(leaky(asrc[(size_t)s * 4 + myh] + ad_my) - m_my) * inv_my;
    const half4 hv = *(const half4*)&h1[(size_t)s * 256 + 4 * lane];
    acc.x = fmaf(alpha, (float)hv[0], acc.x);
    acc.y = fmaf(alpha, (float)hv[1], acc.y);
    acc.z = fmaf(alpha, (float)hv[2], acc.z);
    acc.w = fmaf(alpha, (float)hv[3], acc.w);
  }

  const float a = prelu_a[0];
  const int c = 4 * lane;
  const float4 bv = *(const float4*)&b1[c];
  float4 r;
  r.x = acc.x + bv.x; r.x = r.x >= 0.f ? r.x : a * r.x;
  r.y = acc.y + bv.y; r.y = r.y >= 0.f ? r.y : a * r.y;
  r.z = acc.z + bv.z; r.z = r.z >= 0.f ? r.z : a * r.z;
  r.w = acc.w + bv.w; r.w = r.w >= 0.f ? r.w : a * r.w;

  ushort4 hi, lo;
  hi.x = f2bf(r.x); lo.x = f2bf(r.x - bf2f(hi.x));
  hi.y = f2bf(r.y); lo.y = f2bf(r.y - bf2f(hi.y));
  hi.z = f2bf(r.z); lo.z = f2bf(r.z - bf2f(hi.z));
  hi.w = f2bf(r.w); lo.w = f2bf(r.w - bf2f(hi.w));
  *(ushort4*)&out_hi[(size_t)dst * 256 + c] = hi;
  *(ushort4*)&out_lo[(size_t)dst * 256 + c] = lo;
}

// ---------------- Aggregation conv2: softmax, weighted sum (fp16 gather), head-mean, +b2, PReLU, @Wl+bl ----------------

__global__ __launch_bounds__(256) void k_agg2(const _Float16* __restrict__ h2,
                                              const float* __restrict__ asrc,
                                              const float* __restrict__ adst,
                                              const int* __restrict__ rowptr,
                                              const int* __restrict__ esrc,
                                              const float* __restrict__ b2,
                                              const float* __restrict__ prelu_a,
                                              const float* __restrict__ Wl,
                                              const float* __restrict__ bl,
                                              float* __restrict__ out) {
  int gid = blockIdx.x * 256 + threadIdx.x;
  int dst = gid >> 6;
  int lane = threadIdx.x & 63;
  if (dst >= N_NODES) return;
  int beg = rowptr[dst], end = rowptr[dst + 1];

  float ad[4];
#pragma unroll
  for (int h = 0; h < 4; ++h) ad[h] = adst[(size_t)dst * 4 + h];

  float mh[4] = {-INFINITY, -INFINITY, -INFINITY, -INFINITY};
  for (int j = beg + lane; j < end; j += 64) {
    int s = esrc[j];
#pragma unroll
    for (int h = 0; h < 4; ++h) {
      float e = leaky(asrc[(size_t)s * 4 + h] + ad[h]);
      mh[h] = fmaxf(mh[h], e);
    }
  }
#pragma unroll
  for (int off = 1; off < 64; off <<= 1)
#pragma unroll
    for (int h = 0; h < 4; ++h) mh[h] = fmaxf(mh[h], __shfl_xor(mh[h], off));

  float dh[4] = {0.f, 0.f, 0.f, 0.f};
  for (int j = beg + lane; j < end; j += 64) {
    int s = esrc[j];
#pragma unroll
    for (int h = 0; h < 4; ++h) {
      float e = leaky(asrc[(size_t)s * 4 + h] + ad[h]);
      dh[h] += __expf(e - mh[h]);
    }
  }
#pragma unroll
  for (int off = 1; off < 64; off <<= 1)
#pragma unroll
    for (int h = 0; h < 4; ++h) dh[h] += __shfl_xor(dh[h], off);

  const int myh = lane >> 4;
  const float m_my = mh[myh];
  const float inv_my = 1.f / (dh[myh] + 1e-16f);
  const float ad_my = ad[myh];

  float4 acc = make_float4(0.f, 0.f, 0.f, 0.f);
  for (int j = beg; j < end; ++j) {
    int s = esrc[j];
    float alpha = __expf(leaky(asrc[(size_t)s * 4 + myh] + ad_my) - m_my) * inv_my;
    const half4 hv = *(const half4*)&h2[(size_t)s * 256 + 4 * lane];
    acc.x = fmaf(alpha, (float)hv[0], acc.x);
    acc.y = fmaf(alpha, (float)hv[1], acc.y);
    acc.z = fmaf(alpha, (float)hv[2], acc.z);
    acc.w = fmaf(alpha, (float)hv[3], acc.w);
  }

#pragma unroll
  for (int off = 16; off < 64; off <<= 1) {
    acc.x += __shfl_xor(acc.x, off);
    acc.y += __shfl_xor(acc.y, off);
    acc.z += __shfl_xor(acc.z, off);
    acc.w += __shfl_xor(acc.w, off);
  }

  const float a = prelu_a[0];
  const int c0 = 4 * (lane & 15);
  float4 v;
  v.x = 0.25f * acc.x + b2[c0 + 0]; v.x = v.x >= 0.f ? v.x : a * v.x;
  v.y = 0.25f * acc.y + b2[c0 + 1]; v.y = v.y >= 0.f ? v.y : a * v.y;
  v.z = 0.25f * acc.z + b2[c0 + 2]; v.z = v.z >= 0.f ? v.z : a * v.z;
  v.w = 0.25f * acc.w + b2[c0 + 3]; v.w = v.w >= 0.f ? v.w : a * v.w;

  float p = v.x * Wl[c0 + 0] + v.y * Wl[c0 + 1] + v.z * Wl[c0 + 2] + v.w * Wl[c0 + 3];
#pragma unroll
  for (int off = 1; off < 16; off <<= 1) p += __shfl_xor(p, off);

  if (lane == 0) out[dst] = p + bl[0];
}

// ---------------- launch ----------------

static inline int cdiv(int a, int b) { return (a + b - 1) / b; }

extern "C" void kernel_launch(void* const* d_in, const int* in_sizes, int n_in,
                              void* d_out, int out_size, void* d_ws, size_t ws_size,
                              hipStream_t stream) {
  const float* x   = (const float*)d_in[0];
  const int*   ei  = (const int*)d_in[1];
  const float* W1  = (const float*)d_in[2];
  const float* as1 = (const float*)d_in[3];
  const float* ad1 = (const float*)d_in[4];
  const float* b1  = (const float*)d_in[5];
  const float* W2  = (const float*)d_in[6];
  const float* as2 = (const float*)d_in[7];
  const float* ad2 = (const float*)d_in[8];
  const float* b2  = (const float*)d_in[9];
  const float* pa  = (const float*)d_in[10];
  const float* Wl  = (const float*)d_in[11];
  const float* bl  = (const float*)d_in[12];
  float* out = (float*)d_out;

  char* ws = (char*)d_ws;
  size_t off = 0;
  auto alloc = [&](size_t bytes) -> void* {
    void* p = ws + off;
    off += (bytes + 255) & ~(size_t)255;
    return p;
  };

  _Float16* hbufA = (_Float16*)alloc((size_t)N_NODES * 256 * sizeof(_Float16)); // h1, then h2 (fp16)
  // R1: x_hi/x_lo live here during conv1; h1p_hi/h1p_lo overwrite after agg1
  unsigned short* R1 = (unsigned short*)alloc((size_t)N_NODES * 256 * 2 * sizeof(unsigned short));
  unsigned short* x_hi   = R1;                                // [N][128]
  unsigned short* x_lo   = R1 + (size_t)N_NODES * 128;
  unsigned short* h1p_hi = R1;                                // [N][256]
  unsigned short* h1p_lo = R1 + (size_t)N_NODES * 256;

  float* asrc1 = (float*)alloc((size_t)N_NODES * 4 * sizeof(float));
  float* adst1 = (float*)alloc((size_t)N_NODES * 4 * sizeof(float));
  float* asrc2 = (float*)alloc((size_t)N_NODES * 4 * sizeof(float));
  float* adst2 = (float*)alloc((size_t)N_NODES * 4 * sizeof(float));

  unsigned short* Wt1_hi  = (unsigned short*)alloc(256 * 128 * sizeof(unsigned short));
  unsigned short* Wt1_lo  = (unsigned short*)alloc(256 * 128 * sizeof(unsigned short));
  unsigned short* Wat1_hi = (unsigned short*)alloc(16 * 128 * sizeof(unsigned short));
  unsigned short* Wat1_lo = (unsigned short*)alloc(16 * 128 * sizeof(unsigned short));
  unsigned short* Wt2_hi  = (unsigned short*)alloc(256 * 256 * sizeof(unsigned short));
  unsigned short* Wt2_lo  = (unsigned short*)alloc(256 * 256 * sizeof(unsigned short));
  unsigned short* Wat2_hi = (unsigned short*)alloc(16 * 256 * sizeof(unsigned short));
  unsigned short* Wat2_lo = (unsigned short*)alloc(16 * 256 * sizeof(unsigned short));

  int* counts  = (int*)alloc((size_t)N_NODES * sizeof(int));
  int* partial = (int*)alloc((size_t)N_NODES * sizeof(int));
  int* rowptr  = (int*)alloc((size_t)(N_NODES + 1) * sizeof(int));
  int* fill    = (int*)alloc((size_t)N_NODES * sizeof(int));
  int* esrc    = (int*)alloc((size_t)E_TOT * sizeof(int));
  int* blockSums = (int*)alloc(2048 * sizeof(int));

  const int NB = cdiv(N_NODES, 256);

  // CSR build
  k_init_counts<<<NB, 256, 0, stream>>>(counts);
  k_hist<<<cdiv(N_EDGES, 256), 256, 0, stream>>>(ei, counts);
  k_scan1<<<NB, 256, 0, stream>>>(counts, partial, blockSums);
  k_scan2<<<1, 512, 0, stream>>>(blockSums, NB);
  k_scan3<<<NB, 256, 0, stream>>>(partial, blockSums, rowptr, fill);
  k_scatter<<<cdiv(E_TOT, 256), 256, 0, stream>>>(ei, fill, esrc);

  // weight prep
  k_wconv<128><<<cdiv(128 * 256, 256), 256, 0, stream>>>(W1, Wt1_hi, Wt1_lo);
  k_wa<128><<<128, 256, 0, stream>>>(W1, as1, ad1, Wat1_hi, Wat1_lo);
  k_wconv<256><<<cdiv(256 * 256, 256), 256, 0, stream>>>(W2, Wt2_hi, Wt2_lo);
  k_wa<256><<<256, 256, 0, stream>>>(W2, as2, ad2, Wat2_hi, Wat2_lo);

  // x -> bf16 hi/lo
  k_conv_x<<<N_NODES * 128 / 4 / 256, 256, 0, stream>>>(x, x_hi, x_lo);

  const int GEMM_GRID = cdiv(N_NODES, 64);  // 1563

  // conv1
  k_gemm_mfma<128><<<GEMM_GRID, 256, 0, stream>>>(x_hi, x_lo, Wt1_hi, Wt1_lo,
                                                  Wat1_hi, Wat1_lo, hbufA, asrc1, adst1);
  k_agg1<<<N_NODES * 64 / 256, 256, 0, stream>>>(hbufA, asrc1, adst1, rowptr, esrc,
                                                 b1, pa, h1p_hi, h1p_lo);

  // conv2
  k_gemm_mfma<256><<<GEMM_GRID, 256, 0, stream>>>(h1p_hi, h1p_lo, Wt2_hi, Wt2_lo,
                                                  Wat2_hi, Wat2_lo, hbufA, asrc2, adst2);
  k_agg2<<<N_NODES * 64 / 256, 256, 0, stream>>>(hbufA, asrc2, adst2, rowptr, esrc,
                                                 b2, pa, Wl, bl, out);
}

// Round 4
// 440.405 us; speedup vs baseline: 1.8344x; 1.2027x over previous
//
#include <hip/hip_runtime.h>
#include <cstdint>
#include <cstddef>

static constexpr int N_NODES = 100000;
static constexpr int N_EDGES = 600000;
static constexpr int E_TOT   = N_EDGES + N_NODES;
static constexpr float NEG_SLOPE = 0.2f;

typedef __attribute__((ext_vector_type(8))) short bf16x8;   // 8 bf16 (4 VGPR)
typedef __attribute__((ext_vector_type(4))) float f32x4;    // 4 fp32
typedef __attribute__((ext_vector_type(4))) _Float16 half4; // 4 fp16 (8B)

__device__ __forceinline__ float leaky(float x) { return x >= 0.f ? x : NEG_SLOPE * x; }

__device__ __forceinline__ unsigned short f2bf(float f) {  // RNE to bf16
  unsigned u = __float_as_uint(f);
  u = u + 0x7fffu + ((u >> 16) & 1u);
  return (unsigned short)(u >> 16);
}
__device__ __forceinline__ float bf2f(unsigned short h) {
  return __uint_as_float((unsigned)h << 16);
}

// async global -> LDS, 16 bytes per lane. Dest is wave-uniform base + lane*16.
__device__ __forceinline__ void gload16(const unsigned short* g, unsigned short* l) {
  __builtin_amdgcn_global_load_lds(
      (const __attribute__((address_space(1))) unsigned int*)g,
      (__attribute__((address_space(3))) unsigned int*)l,
      16, 0, 0);
}

// ---------------- CSR build ----------------

__global__ __launch_bounds__(256) void k_init_counts(int* __restrict__ counts) {
  int i = blockIdx.x * 256 + threadIdx.x;
  if (i < N_NODES) counts[i] = 1;   // self-loop
}

__global__ __launch_bounds__(256) void k_hist(const int* __restrict__ ei, int* __restrict__ counts) {
  int e = blockIdx.x * 256 + threadIdx.x;
  if (e < N_EDGES) atomicAdd(&counts[ei[N_EDGES + e]], 1);
}

__global__ __launch_bounds__(256) void k_scan1(const int* __restrict__ counts,
                                               int* __restrict__ partial,
                                               int* __restrict__ blockSums) {
  __shared__ int tmp[256];
  int tid = threadIdx.x;
  int i = blockIdx.x * 256 + tid;
  int v = (i < N_NODES) ? counts[i] : 0;
  tmp[tid] = v;
  __syncthreads();
  for (int off = 1; off < 256; off <<= 1) {
    int t = (tid >= off) ? tmp[tid - off] : 0;
    __syncthreads();
    tmp[tid] += t;
    __syncthreads();
  }
  if (i < N_NODES) partial[i] = tmp[tid] - v;
  if (tid == 255) blockSums[blockIdx.x] = tmp[tid];
}

__global__ __launch_bounds__(512) void k_scan2(int* __restrict__ blockSums, int nb) {
  __shared__ int tmp[512];
  int tid = threadIdx.x;
  int v = (tid < nb) ? blockSums[tid] : 0;
  tmp[tid] = v;
  __syncthreads();
  for (int off = 1; off < 512; off <<= 1) {
    int t = (tid >= off) ? tmp[tid - off] : 0;
    __syncthreads();
    tmp[tid] += t;
    __syncthreads();
  }
  if (tid < nb) blockSums[tid] = tmp[tid] - v;
}

__global__ __launch_bounds__(256) void k_scan3(const int* __restrict__ partial,
                                               const int* __restrict__ blockSums,
                                               int* __restrict__ rowptr,
                                               int* __restrict__ fill) {
  int i = blockIdx.x * 256 + threadIdx.x;
  if (i < N_NODES) {
    int v = partial[i] + blockSums[blockIdx.x];
    rowptr[i] = v;
    fill[i] = v;
  }
  if (i == 0) rowptr[N_NODES] = E_TOT;
}

__global__ __launch_bounds__(256) void k_scatter(const int* __restrict__ ei,
                                                 int* __restrict__ fill,
                                                 int* __restrict__ esrc) {
  int i = blockIdx.x * 256 + threadIdx.x;
  if (i >= E_TOT) return;
  int s, d;
  if (i < N_EDGES) { s = ei[i]; d = ei[N_EDGES + i]; }
  else             { s = i - N_EDGES; d = s; }
  int pos = atomicAdd(&fill[d], 1);
  esrc[pos] = s;
}

// ---------------- weight prep ----------------

template <int K>
__global__ __launch_bounds__(256) void k_wconv(const float* __restrict__ W,
                                               unsigned short* __restrict__ Wt_hi,
                                               unsigned short* __restrict__ Wt_lo) {
  int t = blockIdx.x * 256 + threadIdx.x;
  if (t >= K * 256) return;
  int k = t >> 8, c = t & 255;
  float v = W[t];
  unsigned short hi = f2bf(v);
  Wt_hi[(size_t)c * K + k] = hi;
  Wt_lo[(size_t)c * K + k] = f2bf(v - bf2f(hi));
}

template <int K>
__global__ __launch_bounds__(256) void k_wa(const float* __restrict__ W,
                                            const float* __restrict__ att_s,
                                            const float* __restrict__ att_d,
                                            unsigned short* __restrict__ Wat_hi,
                                            unsigned short* __restrict__ Wat_lo) {
  int k = blockIdx.x;
  int h = threadIdx.x >> 6, c = threadIdx.x & 63;
  float wv = W[(size_t)k * 256 + h * 64 + c];
  float ps = wv * att_s[h * 64 + c];
  float pd = wv * att_d[h * 64 + c];
#pragma unroll
  for (int off = 32; off > 0; off >>= 1) {
    ps += __shfl_xor(ps, off);
    pd += __shfl_xor(pd, off);
  }
  if (c == 0) {
    unsigned short hi = f2bf(ps);
    Wat_hi[(size_t)h * K + k] = hi;
    Wat_lo[(size_t)h * K + k] = f2bf(ps - bf2f(hi));
    hi = f2bf(pd);
    Wat_hi[(size_t)(4 + h) * K + k] = hi;
    Wat_lo[(size_t)(4 + h) * K + k] = f2bf(pd - bf2f(hi));
  }
  if (threadIdx.x >= 8 && threadIdx.x < 16) {
    Wat_hi[(size_t)threadIdx.x * K + k] = 0;
    Wat_lo[(size_t)threadIdx.x * K + k] = 0;
  }
}

// ---------------- x -> bf16 hi/lo ----------------

__global__ __launch_bounds__(256) void k_conv_x(const float* __restrict__ X,
                                                unsigned short* __restrict__ Xhi,
                                                unsigned short* __restrict__ Xlo) {
  size_t t = (size_t)blockIdx.x * 256 + threadIdx.x;  // handles 4 floats
  float4 v = *(const float4*)&X[t * 4];
  ushort4 hi, lo;
  hi.x = f2bf(v.x); lo.x = f2bf(v.x - bf2f(hi.x));
  hi.y = f2bf(v.y); lo.y = f2bf(v.y - bf2f(hi.y));
  hi.z = f2bf(v.z); lo.z = f2bf(v.z - bf2f(hi.z));
  hi.w = f2bf(v.w); lo.w = f2bf(v.w - bf2f(hi.w));
  *(ushort4*)&Xhi[t * 4] = hi;
  *(ushort4*)&Xlo[t * 4] = lo;
}

// ---------------- MFMA GEMM: H[N,256] = A[N,K] @ W[K,256], split bf16 hi/lo ----------------
// 2-phase pipeline: double-buffered LDS staged via global_load_lds (width 16).
// Block: 256 thr = 4 waves, tile 64 rows x 256 cols; wave w owns cols 64w..64w+63.
// LDS per buffer (shorts): Ah[64][32] @0, Al @2048, Bh[256][32] @4096, Bl @12288.
// Chunk-XOR swizzle (ch ^= row&3) applied via pre-swizzled global source; reads
// use the same XOR -> ds_read_b128 bank conflicts drop from 8-way to ~4/2-way.
// Wave 0 additionally computes attention dots (Wa-tile B-frags direct from global).

template <int K>
__global__ __launch_bounds__(256, 2) void k_gemm_mfma(
    const unsigned short* __restrict__ Ahi, const unsigned short* __restrict__ Alo,
    const unsigned short* __restrict__ Bhi, const unsigned short* __restrict__ Blo,
    const unsigned short* __restrict__ Whi, const unsigned short* __restrict__ Wlo,
    _Float16* __restrict__ H, float* __restrict__ asrc, float* __restrict__ adst) {
  __shared__ __align__(16) unsigned short lds[2][20480];   // 80 KB

  const int tid = threadIdx.x;
  const int w = tid >> 6, lane = tid & 63;
  const int lhi = lane >> 4, llo = lane & 15;
  const int wrow = blockIdx.x * 64;
  const int wcol = w * 64;

  // ---- staging source addresses (per thread), swizzled chunk ----
  const int sr = tid >> 2;                 // tile row handled by this thread (0..63)
  const int sc = (tid & 3) ^ (sr & 3);     // swizzled source chunk
  int ar = wrow + sr; if (ar > N_NODES - 1) ar = N_NODES - 1;
  const unsigned short* gAh = &Ahi[(size_t)ar * K + sc * 8];
  const unsigned short* gAl = &Alo[(size_t)ar * K + sc * 8];
  const unsigned short* gB0h = &Bhi[(size_t)(0 * 64 + sr) * K + sc * 8];
  const unsigned short* gB1h = &Bhi[(size_t)(1 * 64 + sr) * K + sc * 8];
  const unsigned short* gB2h = &Bhi[(size_t)(2 * 64 + sr) * K + sc * 8];
  const unsigned short* gB3h = &Bhi[(size_t)(3 * 64 + sr) * K + sc * 8];
  const unsigned short* gB0l = &Blo[(size_t)(0 * 64 + sr) * K + sc * 8];
  const unsigned short* gB1l = &Blo[(size_t)(1 * 64 + sr) * K + sc * 8];
  const unsigned short* gB2l = &Blo[(size_t)(2 * 64 + sr) * K + sc * 8];
  const unsigned short* gB3l = &Blo[(size_t)(3 * 64 + sr) * K + sc * 8];
  const int wb = w * 512;                  // per-wave dest base offset (shorts)

  // attention-tile fragment sources (wave 0 only; L2-hot)
  const unsigned short* gWh = &Whi[(size_t)llo * K + lhi * 8];
  const unsigned short* gWl = &Wlo[(size_t)llo * K + lhi * 8];

  f32x4 acc[4][4] = {};
  f32x4 acca[4] = {};

  // fragment-read LDS offsets (swizzled chunk: lhi ^ (row&3), row&3 == llo&3)
  const int ach = (lhi ^ (llo & 3)) * 8;

  auto STAGE = [&](int buf, int kc) {
    unsigned short* L = lds[buf];
    gload16(gAh + kc, L + 0 + wb);
    gload16(gAl + kc, L + 2048 + wb);
    gload16(gB0h + kc, L + 4096 + 0 * 2048 + wb);
    gload16(gB1h + kc, L + 4096 + 1 * 2048 + wb);
    gload16(gB2h + kc, L + 4096 + 2 * 2048 + wb);
    gload16(gB3h + kc, L + 4096 + 3 * 2048 + wb);
    gload16(gB0l + kc, L + 12288 + 0 * 2048 + wb);
    gload16(gB1l + kc, L + 12288 + 1 * 2048 + wb);
    gload16(gB2l + kc, L + 12288 + 2 * 2048 + wb);
    gload16(gB3l + kc, L + 12288 + 3 * 2048 + wb);
  };

  STAGE(0, 0);
  __syncthreads();   // compiler drains vmcnt before barrier -> buf0 ready

  constexpr int NT = K / 32;
  int cur = 0;
#pragma unroll 2
  for (int t = 0; t < NT; ++t) {
    if (t + 1 < NT) STAGE(cur ^ 1, (t + 1) * 32);

    bf16x8 wh{}, wlv{};
    if (w == 0) {            // issue early; consumed after main MFMAs
      wh  = *(const bf16x8*)&gWh[t * 32];
      wlv = *(const bf16x8*)&gWl[t * 32];
    }

    const unsigned short* L = lds[cur];
    bf16x8 ah[4], al[4], bh[4], bl[4];
#pragma unroll
    for (int rt = 0; rt < 4; ++rt) {
      ah[rt] = *(const bf16x8*)&L[(rt * 16 + llo) * 32 + ach];
      al[rt] = *(const bf16x8*)&L[2048 + (rt * 16 + llo) * 32 + ach];
    }
#pragma unroll
    for (int ct = 0; ct < 4; ++ct) {
      bh[ct] = *(const bf16x8*)&L[4096 + (wcol + ct * 16 + llo) * 32 + ach];
      bl[ct] = *(const bf16x8*)&L[12288 + (wcol + ct * 16 + llo) * 32 + ach];
    }

#pragma unroll
    for (int ct = 0; ct < 4; ++ct)
#pragma unroll
      for (int rt = 0; rt < 4; ++rt) {
        acc[rt][ct] = __builtin_amdgcn_mfma_f32_16x16x32_bf16(ah[rt], bh[ct], acc[rt][ct], 0, 0, 0);
        acc[rt][ct] = __builtin_amdgcn_mfma_f32_16x16x32_bf16(al[rt], bh[ct], acc[rt][ct], 0, 0, 0);
        acc[rt][ct] = __builtin_amdgcn_mfma_f32_16x16x32_bf16(ah[rt], bl[ct], acc[rt][ct], 0, 0, 0);
      }
    if (w == 0) {
#pragma unroll
      for (int rt = 0; rt < 4; ++rt) {
        acca[rt] = __builtin_amdgcn_mfma_f32_16x16x32_bf16(ah[rt], wh, acca[rt], 0, 0, 0);
        acca[rt] = __builtin_amdgcn_mfma_f32_16x16x32_bf16(al[rt], wh, acca[rt], 0, 0, 0);
        acca[rt] = __builtin_amdgcn_mfma_f32_16x16x32_bf16(ah[rt], wlv, acca[rt], 0, 0, 0);
      }
    }
    __syncthreads();  // stage of buf^1 complete + all reads of buf[cur] done
    cur ^= 1;
  }

  // C/D layout: col = lane&15, row = (lane>>4)*4 + reg
#pragma unroll
  for (int rt = 0; rt < 4; ++rt) {
    const int r0 = wrow + rt * 16 + lhi * 4;
#pragma unroll
    for (int ct = 0; ct < 4; ++ct) {
      const int cc = wcol + ct * 16 + llo;
#pragma unroll
      for (int e = 0; e < 4; ++e) {
        int r = r0 + e;
        if (r < N_NODES) H[(size_t)r * 256 + cc] = (_Float16)acc[rt][ct][e];
      }
    }
    if (w == 0 && llo < 8) {
#pragma unroll
      for (int e = 0; e < 4; ++e) {
        int r = r0 + e;
        if (r < N_NODES) {
          float v = acca[rt][e];
          if (llo < 4) asrc[(size_t)r * 4 + llo] = v;
          else         adst[(size_t)r * 4 + (llo - 4)] = v;
        }
      }
    }
  }
}

// ---------------- Aggregation conv1: softmax, weighted sum (fp16 gather), +b1, PReLU, -> bf16 hi/lo ----------------

__global__ __launch_bounds__(256) void k_agg1(const _Float16* __restrict__ h1,
                                              const float* __restrict__ asrc,
                                              const float* __restrict__ adst,
                                              const int* __restrict__ rowptr,
                                              const int* __restrict__ esrc,
                                              const float* __restrict__ b1,
                                              const float* __restrict__ prelu_a,
                                              unsigned short* __restrict__ out_hi,
                                              unsigned short* __restrict__ out_lo) {
  int gid = blockIdx.x * 256 + threadIdx.x;
  int dst = gid >> 6;
  int lane = threadIdx.x & 63;
  if (dst >= N_NODES) return;
  int beg = rowptr[dst], end = rowptr[dst + 1];

  float ad[4];
#pragma unroll
  for (int h = 0; h < 4; ++h) ad[h] = adst[(size_t)dst * 4 + h];

  float mh[4] = {-INFINITY, -INFINITY, -INFINITY, -INFINITY};
  for (int j = beg + lane; j < end; j += 64) {
    int s = esrc[j];
#pragma unroll
    for (int h = 0; h < 4; ++h) {
      float e = leaky(asrc[(size_t)s * 4 + h] + ad[h]);
      mh[h] = fmaxf(mh[h], e);
    }
  }
#pragma unroll
  for (int off = 1; off < 64; off <<= 1)
#pragma unroll
    for (int h = 0; h < 4; ++h) mh[h] = fmaxf(mh[h], __shfl_xor(mh[h], off));

  float dh[4] = {0.f, 0.f, 0.f, 0.f};
  for (int j = beg + lane; j < end; j += 64) {
    int s = esrc[j];
#pragma unroll
    for (int h = 0; h < 4; ++h) {
      float e = leaky(asrc[(size_t)s * 4 + h] + ad[h]);
      dh[h] += __expf(e - mh[h]);
    }
  }
#pragma unroll
  for (int off = 1; off < 64; off <<= 1)
#pragma unroll
    for (int h = 0; h < 4; ++h) dh[h] += __shfl_xor(dh[h], off);

  const int myh = lane >> 4;
  const float m_my = mh[myh];
  const float inv_my = 1.f / (dh[myh] + 1e-16f);
  const float ad_my = ad[myh];

  float4 acc = make_float4(0.f, 0.f, 0.f, 0.f);
  for (int j = beg; j < end; ++j) {
    int s = esrc[j];
    float alpha = __expf(leaky(asrc[(size_t)s * 4 + myh] + ad_my) - m_my) * inv_my;
    const half4 hv = *(const half4*)&h1[(size_t)s * 256 + 4 * lane];
    acc.x = fmaf(alpha, (float)hv[0], acc.x);
    acc.y = fmaf(alpha, (float)hv[1], acc.y);
    acc.z = fmaf(alpha, (float)hv[2], acc.z);
    acc.w = fmaf(alpha, (float)hv[3], acc.w);
  }

  const float a = prelu_a[0];
  const int c = 4 * lane;
  const float4 bv = *(const float4*)&b1[c];
  float4 r;
  r.x = acc.x + bv.x; r.x = r.x >= 0.f ? r.x : a * r.x;
  r.y = acc.y + bv.y; r.y = r.y >= 0.f ? r.y : a * r.y;
  r.z = acc.z + bv.z; r.z = r.z >= 0.f ? r.z : a * r.z;
  r.w = acc.w + bv.w; r.w = r.w >= 0.f ? r.w : a * r.w;

  ushort4 hi, lo;
  hi.x = f2bf(r.x); lo.x = f2bf(r.x - bf2f(hi.x));
  hi.y = f2bf(r.y); lo.y = f2bf(r.y - bf2f(hi.y));
  hi.z = f2bf(r.z); lo.z = f2bf(r.z - bf2f(hi.z));
  hi.w = f2bf(r.w); lo.w = f2bf(r.w - bf2f(hi.w));
  *(ushort4*)&out_hi[(size_t)dst * 256 + c] = hi;
  *(ushort4*)&out_lo[(size_t)dst * 256 + c] = lo;
}

// ---------------- Aggregation conv2: softmax, weighted sum (fp16 gather), head-mean, +b2, PReLU, @Wl+bl ----------------

__global__ __launch_bounds__(256) void k_agg2(const _Float16* __restrict__ h2,
                                              const float* __restrict__ asrc,
                                              const float* __restrict__ adst,
                                              const int* __restrict__ rowptr,
                                              const int* __restrict__ esrc,
                                              const float* __restrict__ b2,
                                              const float* __restrict__ prelu_a,
                                              const float* __restrict__ Wl,
                                              const float* __restrict__ bl,
                                              float* __restrict__ out) {
  int gid = blockIdx.x * 256 + threadIdx.x;
  int dst = gid >> 6;
  int lane = threadIdx.x & 63;
  if (dst >= N_NODES) return;
  int beg = rowptr[dst], end = rowptr[dst + 1];

  float ad[4];
#pragma unroll
  for (int h = 0; h < 4; ++h) ad[h] = adst[(size_t)dst * 4 + h];

  float mh[4] = {-INFINITY, -INFINITY, -INFINITY, -INFINITY};
  for (int j = beg + lane; j < end; j += 64) {
    int s = esrc[j];
#pragma unroll
    for (int h = 0; h < 4; ++h) {
      float e = leaky(asrc[(size_t)s * 4 + h] + ad[h]);
      mh[h] = fmaxf(mh[h], e);
    }
  }
#pragma unroll
  for (int off = 1; off < 64; off <<= 1)
#pragma unroll
    for (int h = 0; h < 4; ++h) mh[h] = fmaxf(mh[h], __shfl_xor(mh[h], off));

  float dh[4] = {0.f, 0.f, 0.f, 0.f};
  for (int j = beg + lane; j < end; j += 64) {
    int s = esrc[j];
#pragma unroll
    for (int h = 0; h < 4; ++h) {
      float e = leaky(asrc[(size_t)s * 4 + h] + ad[h]);
      dh[h] += __expf(e - mh[h]);
    }
  }
#pragma unroll
  for (int off = 1; off < 64; off <<= 1)
#pragma unroll
    for (int h = 0; h < 4; ++h) dh[h] += __shfl_xor(dh[h], off);

  const int myh = lane >> 4;
  const float m_my = mh[myh];
  const float inv_my = 1.f / (dh[myh] + 1e-16f);
  const float ad_my = ad[myh];

  float4 acc = make_float4(0.f, 0.f, 0.f, 0.f);
  for (int j = beg; j < end; ++j) {
    int s = esrc[j];
    float alpha = __expf(leaky(asrc[(size_t)s * 4 + myh] + ad_my) - m_my) * inv_my;
    const half4 hv = *(const half4*)&h2[(size_t)s * 256 + 4 * lane];
    acc.x = fmaf(alpha, (float)hv[0], acc.x);
    acc.y = fmaf(alpha, (float)hv[1], acc.y);
    acc.z = fmaf(alpha, (float)hv[2], acc.z);
    acc.w = fmaf(alpha, (float)hv[3], acc.w);
  }

#pragma unroll
  for (int off = 16; off < 64; off <<= 1) {
    acc.x += __shfl_xor(acc.x, off);
    acc.y += __shfl_xor(acc.y, off);
    acc.z += __shfl_xor(acc.z, off);
    acc.w += __shfl_xor(acc.w, off);
  }

  const float a = prelu_a[0];
  const int c0 = 4 * (lane & 15);
  float4 v;
  v.x = 0.25f * acc.x + b2[c0 + 0]; v.x = v.x >= 0.f ? v.x : a * v.x;
  v.y = 0.25f * acc.y + b2[c0 + 1]; v.y = v.y >= 0.f ? v.y : a * v.y;
  v.z = 0.25f * acc.z + b2[c0 + 2]; v.z = v.z >= 0.f ? v.z : a * v.z;
  v.w = 0.25f * acc.w + b2[c0 + 3]; v.w = v.w >= 0.f ? v.w : a * v.w;

  float p = v.x * Wl[c0 + 0] + v.y * Wl[c0 + 1] + v.z * Wl[c0 + 2] + v.w * Wl[c0 + 3];
#pragma unroll
  for (int off = 1; off < 16; off <<= 1) p += __shfl_xor(p, off);

  if (lane == 0) out[dst] = p + bl[0];
}

// ---------------- launch ----------------

static inline int cdiv(int a, int b) { return (a + b - 1) / b; }

extern "C" void kernel_launch(void* const* d_in, const int* in_sizes, int n_in,
                              void* d_out, int out_size, void* d_ws, size_t ws_size,
                              hipStream_t stream) {
  const float* x   = (const float*)d_in[0];
  const int*   ei  = (const int*)d_in[1];
  const float* W1  = (const float*)d_in[2];
  const float* as1 = (const float*)d_in[3];
  const float* ad1 = (const float*)d_in[4];
  const float* b1  = (const float*)d_in[5];
  const float* W2  = (const float*)d_in[6];
  const float* as2 = (const float*)d_in[7];
  const float* ad2 = (const float*)d_in[8];
  const float* b2  = (const float*)d_in[9];
  const float* pa  = (const float*)d_in[10];
  const float* Wl  = (const float*)d_in[11];
  const float* bl  = (const float*)d_in[12];
  float* out = (float*)d_out;

  char* ws = (char*)d_ws;
  size_t off = 0;
  auto alloc = [&](size_t bytes) -> void* {
    void* p = ws + off;
    off += (bytes + 255) & ~(size_t)255;
    return p;
  };

  _Float16* hbufA = (_Float16*)alloc((size_t)N_NODES * 256 * sizeof(_Float16)); // h1, then h2 (fp16)
  // R1: x_hi/x_lo live here during conv1; h1p_hi/h1p_lo overwrite after agg1
  unsigned short* R1 = (unsigned short*)alloc((size_t)N_NODES * 256 * 2 * sizeof(unsigned short));
  unsigned short* x_hi   = R1;                                // [N][128]
  unsigned short* x_lo   = R1 + (size_t)N_NODES * 128;
  unsigned short* h1p_hi = R1;                                // [N][256]
  unsigned short* h1p_lo = R1 + (size_t)N_NODES * 256;

  float* asrc1 = (float*)alloc((size_t)N_NODES * 4 * sizeof(float));
  float* adst1 = (float*)alloc((size_t)N_NODES * 4 * sizeof(float));
  float* asrc2 = (float*)alloc((size_t)N_NODES * 4 * sizeof(float));
  float* adst2 = (float*)alloc((size_t)N_NODES * 4 * sizeof(float));

  unsigned short* Wt1_hi  = (unsigned short*)alloc(256 * 128 * sizeof(unsigned short));
  unsigned short* Wt1_lo  = (unsigned short*)alloc(256 * 128 * sizeof(unsigned short));
  unsigned short* Wat1_hi = (unsigned short*)alloc(16 * 128 * sizeof(unsigned short));
  unsigned short* Wat1_lo = (unsigned short*)alloc(16 * 128 * sizeof(unsigned short));
  unsigned short* Wt2_hi  = (unsigned short*)alloc(256 * 256 * sizeof(unsigned short));
  unsigned short* Wt2_lo  = (unsigned short*)alloc(256 * 256 * sizeof(unsigned short));
  unsigned short* Wat2_hi = (unsigned short*)alloc(16 * 256 * sizeof(unsigned short));
  unsigned short* Wat2_lo = (unsigned short*)alloc(16 * 256 * sizeof(unsigned short));

  int* counts  = (int*)alloc((size_t)N_NODES * sizeof(int));
  int* partial = (int*)alloc((size_t)N_NODES * sizeof(int));
  int* rowptr  = (int*)alloc((size_t)(N_NODES + 1) * sizeof(int));
  int* fill    = (int*)alloc((size_t)N_NODES * sizeof(int));
  int* esrc    = (int*)alloc((size_t)E_TOT * sizeof(int));
  int* blockSums = (int*)alloc(2048 * sizeof(int));

  const int NB = cdiv(N_NODES, 256);

  // CSR build
  k_init_counts<<<NB, 256, 0, stream>>>(counts);
  k_hist<<<cdiv(N_EDGES, 256), 256, 0, stream>>>(ei, counts);
  k_scan1<<<NB, 256, 0, stream>>>(counts, partial, blockSums);
  k_scan2<<<1, 512, 0, stream>>>(blockSums, NB);
  k_scan3<<<NB, 256, 0, stream>>>(partial, blockSums, rowptr, fill);
  k_scatter<<<cdiv(E_TOT, 256), 256, 0, stream>>>(ei, fill, esrc);

  // weight prep
  k_wconv<128><<<cdiv(128 * 256, 256), 256, 0, stream>>>(W1, Wt1_hi, Wt1_lo);
  k_wa<128><<<128, 256, 0, stream>>>(W1, as1, ad1, Wat1_hi, Wat1_lo);
  k_wconv<256><<<cdiv(256 * 256, 256), 256, 0, stream>>>(W2, Wt2_hi, Wt2_lo);
  k_wa<256><<<256, 256, 0, stream>>>(W2, as2, ad2, Wat2_hi, Wat2_lo);

  // x -> bf16 hi/lo
  k_conv_x<<<N_NODES * 128 / 4 / 256, 256, 0, stream>>>(x, x_hi, x_lo);

  const int GEMM_GRID = cdiv(N_NODES, 64);  // 1563

  // conv1
  k_gemm_mfma<128><<<GEMM_GRID, 256, 0, stream>>>(x_hi, x_lo, Wt1_hi, Wt1_lo,
                                                  Wat1_hi, Wat1_lo, hbufA, asrc1, adst1);
  k_agg1<<<N_NODES * 64 / 256, 256, 0, stream>>>(hbufA, asrc1, adst1, rowptr, esrc,
                                                 b1, pa, h1p_hi, h1p_lo);

  // conv2
  k_gemm_mfma<256><<<GEMM_GRID, 256, 0, stream>>>(h1p_hi, h1p_lo, Wt2_hi, Wt2_lo,
                                                  Wat2_hi, Wat2_lo, hbufA, asrc2, adst2);
  k_agg2<<<N_NODES * 64 / 256, 256, 0, stream>>>(hbufA, asrc2, adst2, rowptr, esrc,
                                                 b2, pa, Wl, bl, out);
}

// Round 5
// 439.532 us; speedup vs baseline: 1.8380x; 1.0020x over previous
//
#include <hip/hip_runtime.h>
#include <cstdint>
#include <cstddef>

static constexpr int N_NODES = 100000;
static constexpr int N_EDGES = 600000;
static constexpr int E_TOT   = N_EDGES + N_NODES;
static constexpr float NEG_SLOPE = 0.2f;

typedef __attribute__((ext_vector_type(8))) short bf16x8;   // 8 bf16 (4 VGPR)
typedef __attribute__((ext_vector_type(4))) float f32x4;    // 4 fp32
typedef __attribute__((ext_vector_type(4))) _Float16 half4; // 4 fp16 (8B)

__device__ __forceinline__ float leaky(float x) { return x >= 0.f ? x : NEG_SLOPE * x; }

__device__ __forceinline__ unsigned short f2bf(float f) {  // RNE to bf16
  unsigned u = __float_as_uint(f);
  u = u + 0x7fffu + ((u >> 16) & 1u);
  return (unsigned short)(u >> 16);
}
__device__ __forceinline__ float bf2f(unsigned short h) {
  return __uint_as_float((unsigned)h << 16);
}

// async global -> LDS, 16 bytes per lane. Dest is wave-uniform base + lane*16.
__device__ __forceinline__ void gload16(const unsigned short* g, unsigned short* l) {
  __builtin_amdgcn_global_load_lds(
      (const __attribute__((address_space(1))) unsigned int*)g,
      (__attribute__((address_space(3))) unsigned int*)l,
      16, 0, 0);
}

// ---------------- CSR build ----------------

__global__ __launch_bounds__(256) void k_init_counts(int* __restrict__ counts) {
  int i = blockIdx.x * 256 + threadIdx.x;
  if (i < N_NODES) counts[i] = 1;   // self-loop
}

__global__ __launch_bounds__(256) void k_hist(const int* __restrict__ ei, int* __restrict__ counts) {
  int e = blockIdx.x * 256 + threadIdx.x;
  if (e < N_EDGES) atomicAdd(&counts[ei[N_EDGES + e]], 1);
}

__global__ __launch_bounds__(256) void k_scan1(const int* __restrict__ counts,
                                               int* __restrict__ partial,
                                               int* __restrict__ blockSums) {
  __shared__ int tmp[256];
  int tid = threadIdx.x;
  int i = blockIdx.x * 256 + tid;
  int v = (i < N_NODES) ? counts[i] : 0;
  tmp[tid] = v;
  __syncthreads();
  for (int off = 1; off < 256; off <<= 1) {
    int t = (tid >= off) ? tmp[tid - off] : 0;
    __syncthreads();
    tmp[tid] += t;
    __syncthreads();
  }
  if (i < N_NODES) partial[i] = tmp[tid] - v;
  if (tid == 255) blockSums[blockIdx.x] = tmp[tid];
}

__global__ __launch_bounds__(512) void k_scan2(int* __restrict__ blockSums, int nb) {
  __shared__ int tmp[512];
  int tid = threadIdx.x;
  int v = (tid < nb) ? blockSums[tid] : 0;
  tmp[tid] = v;
  __syncthreads();
  for (int off = 1; off < 512; off <<= 1) {
    int t = (tid >= off) ? tmp[tid - off] : 0;
    __syncthreads();
    tmp[tid] += t;
    __syncthreads();
  }
  if (tid < nb) blockSums[tid] = tmp[tid] - v;
}

__global__ __launch_bounds__(256) void k_scan3(const int* __restrict__ partial,
                                               const int* __restrict__ blockSums,
                                               int* __restrict__ rowptr,
                                               int* __restrict__ fill) {
  int i = blockIdx.x * 256 + threadIdx.x;
  if (i < N_NODES) {
    int v = partial[i] + blockSums[blockIdx.x];
    rowptr[i] = v;
    fill[i] = v;
  }
  if (i == 0) rowptr[N_NODES] = E_TOT;
}

__global__ __launch_bounds__(256) void k_scatter(const int* __restrict__ ei,
                                                 int* __restrict__ fill,
                                                 int* __restrict__ esrc) {
  int i = blockIdx.x * 256 + threadIdx.x;
  if (i >= E_TOT) return;
  int s, d;
  if (i < N_EDGES) { s = ei[i]; d = ei[N_EDGES + i]; }
  else             { s = i - N_EDGES; d = s; }
  int pos = atomicAdd(&fill[d], 1);
  esrc[pos] = s;
}

// ---------------- weight prep ----------------

template <int K>
__global__ __launch_bounds__(256) void k_wconv(const float* __restrict__ W,
                                               unsigned short* __restrict__ Wt_hi,
                                               unsigned short* __restrict__ Wt_lo) {
  int t = blockIdx.x * 256 + threadIdx.x;
  if (t >= K * 256) return;
  int k = t >> 8, c = t & 255;
  float v = W[t];
  unsigned short hi = f2bf(v);
  Wt_hi[(size_t)c * K + k] = hi;
  Wt_lo[(size_t)c * K + k] = f2bf(v - bf2f(hi));
}

template <int K>
__global__ __launch_bounds__(256) void k_wa(const float* __restrict__ W,
                                            const float* __restrict__ att_s,
                                            const float* __restrict__ att_d,
                                            unsigned short* __restrict__ Wat_hi,
                                            unsigned short* __restrict__ Wat_lo) {
  int k = blockIdx.x;
  int h = threadIdx.x >> 6, c = threadIdx.x & 63;
  float wv = W[(size_t)k * 256 + h * 64 + c];
  float ps = wv * att_s[h * 64 + c];
  float pd = wv * att_d[h * 64 + c];
#pragma unroll
  for (int off = 32; off > 0; off >>= 1) {
    ps += __shfl_xor(ps, off);
    pd += __shfl_xor(pd, off);
  }
  if (c == 0) {
    unsigned short hi = f2bf(ps);
    Wat_hi[(size_t)h * K + k] = hi;
    Wat_lo[(size_t)h * K + k] = f2bf(ps - bf2f(hi));
    hi = f2bf(pd);
    Wat_hi[(size_t)(4 + h) * K + k] = hi;
    Wat_lo[(size_t)(4 + h) * K + k] = f2bf(pd - bf2f(hi));
  }
  if (threadIdx.x >= 8 && threadIdx.x < 16) {
    Wat_hi[(size_t)threadIdx.x * K + k] = 0;
    Wat_lo[(size_t)threadIdx.x * K + k] = 0;
  }
}

// ---------------- x -> bf16 hi/lo ----------------

__global__ __launch_bounds__(256) void k_conv_x(const float* __restrict__ X,
                                                unsigned short* __restrict__ Xhi,
                                                unsigned short* __restrict__ Xlo) {
  size_t t = (size_t)blockIdx.x * 256 + threadIdx.x;  // handles 4 floats
  float4 v = *(const float4*)&X[t * 4];
  ushort4 hi, lo;
  hi.x = f2bf(v.x); lo.x = f2bf(v.x - bf2f(hi.x));
  hi.y = f2bf(v.y); lo.y = f2bf(v.y - bf2f(hi.y));
  hi.z = f2bf(v.z); lo.z = f2bf(v.z - bf2f(hi.z));
  hi.w = f2bf(v.w); lo.w = f2bf(v.w - bf2f(hi.w));
  *(ushort4*)&Xhi[t * 4] = hi;
  *(ushort4*)&Xlo[t * 4] = lo;
}

// ---------------- MFMA GEMM: H[N,256] = A[N,K] @ W[K,256], split bf16 hi/lo ----------------
// 2-phase pipeline: double-buffered LDS staged via global_load_lds (width 16).
// Block: 256 thr = 4 waves, tile 64 rows x 256 cols; wave w owns cols 64w..64w+63.
// LDS per buffer (shorts): Ah[64][32] @0, Al @2048, Bh[256][32] @4096, Bl @12288.
// Chunk-XOR swizzle (ch ^= row&3) applied via pre-swizzled global source; reads
// use the same XOR -> ds_read_b128 bank conflicts drop from 8-way to ~4/2-way.
// Wave 0 additionally computes attention dots (Wa-tile B-frags direct from global).

template <int K>
__global__ __launch_bounds__(256, 2) void k_gemm_mfma(
    const unsigned short* __restrict__ Ahi, const unsigned short* __restrict__ Alo,
    const unsigned short* __restrict__ Bhi, const unsigned short* __restrict__ Blo,
    const unsigned short* __restrict__ Whi, const unsigned short* __restrict__ Wlo,
    _Float16* __restrict__ H, float* __restrict__ asrc, float* __restrict__ adst) {
  __shared__ __align__(16) unsigned short lds[2][20480];   // 80 KB

  const int tid = threadIdx.x;
  const int w = tid >> 6, lane = tid & 63;
  const int lhi = lane >> 4, llo = lane & 15;
  const int wrow = blockIdx.x * 64;
  const int wcol = w * 64;

  // ---- staging source addresses (per thread), swizzled chunk ----
  const int sr = tid >> 2;                 // tile row handled by this thread (0..63)
  const int sc = (tid & 3) ^ (sr & 3);     // swizzled source chunk
  int ar = wrow + sr; if (ar > N_NODES - 1) ar = N_NODES - 1;
  const unsigned short* gAh = &Ahi[(size_t)ar * K + sc * 8];
  const unsigned short* gAl = &Alo[(size_t)ar * K + sc * 8];
  const unsigned short* gB0h = &Bhi[(size_t)(0 * 64 + sr) * K + sc * 8];
  const unsigned short* gB1h = &Bhi[(size_t)(1 * 64 + sr) * K + sc * 8];
  const unsigned short* gB2h = &Bhi[(size_t)(2 * 64 + sr) * K + sc * 8];
  const unsigned short* gB3h = &Bhi[(size_t)(3 * 64 + sr) * K + sc * 8];
  const unsigned short* gB0l = &Blo[(size_t)(0 * 64 + sr) * K + sc * 8];
  const unsigned short* gB1l = &Blo[(size_t)(1 * 64 + sr) * K + sc * 8];
  const unsigned short* gB2l = &Blo[(size_t)(2 * 64 + sr) * K + sc * 8];
  const unsigned short* gB3l = &Blo[(size_t)(3 * 64 + sr) * K + sc * 8];
  const int wb = w * 512;                  // per-wave dest base offset (shorts)

  // attention-tile fragment sources (wave 0 only; L2-hot)
  const unsigned short* gWh = &Whi[(size_t)llo * K + lhi * 8];
  const unsigned short* gWl = &Wlo[(size_t)llo * K + lhi * 8];

  f32x4 acc[4][4] = {};
  f32x4 acca[4] = {};

  // fragment-read LDS offsets (swizzled chunk: lhi ^ (row&3), row&3 == llo&3)
  const int ach = (lhi ^ (llo & 3)) * 8;

  auto STAGE = [&](int buf, int kc) {
    unsigned short* L = lds[buf];
    gload16(gAh + kc, L + 0 + wb);
    gload16(gAl + kc, L + 2048 + wb);
    gload16(gB0h + kc, L + 4096 + 0 * 2048 + wb);
    gload16(gB1h + kc, L + 4096 + 1 * 2048 + wb);
    gload16(gB2h + kc, L + 4096 + 2 * 2048 + wb);
    gload16(gB3h + kc, L + 4096 + 3 * 2048 + wb);
    gload16(gB0l + kc, L + 12288 + 0 * 2048 + wb);
    gload16(gB1l + kc, L + 12288 + 1 * 2048 + wb);
    gload16(gB2l + kc, L + 12288 + 2 * 2048 + wb);
    gload16(gB3l + kc, L + 12288 + 3 * 2048 + wb);
  };

  STAGE(0, 0);
  __syncthreads();   // compiler drains vmcnt before barrier -> buf0 ready

  constexpr int NT = K / 32;
  int cur = 0;
#pragma unroll 2
  for (int t = 0; t < NT; ++t) {
    if (t + 1 < NT) STAGE(cur ^ 1, (t + 1) * 32);

    bf16x8 wh{}, wlv{};
    if (w == 0) {            // issue early; consumed after main MFMAs
      wh  = *(const bf16x8*)&gWh[t * 32];
      wlv = *(const bf16x8*)&gWl[t * 32];
    }

    const unsigned short* L = lds[cur];
    bf16x8 ah[4], al[4], bh[4], bl[4];
#pragma unroll
    for (int rt = 0; rt < 4; ++rt) {
      ah[rt] = *(const bf16x8*)&L[(rt * 16 + llo) * 32 + ach];
      al[rt] = *(const bf16x8*)&L[2048 + (rt * 16 + llo) * 32 + ach];
    }
#pragma unroll
    for (int ct = 0; ct < 4; ++ct) {
      bh[ct] = *(const bf16x8*)&L[4096 + (wcol + ct * 16 + llo) * 32 + ach];
      bl[ct] = *(const bf16x8*)&L[12288 + (wcol + ct * 16 + llo) * 32 + ach];
    }

#pragma unroll
    for (int ct = 0; ct < 4; ++ct)
#pragma unroll
      for (int rt = 0; rt < 4; ++rt) {
        acc[rt][ct] = __builtin_amdgcn_mfma_f32_16x16x32_bf16(ah[rt], bh[ct], acc[rt][ct], 0, 0, 0);
        acc[rt][ct] = __builtin_amdgcn_mfma_f32_16x16x32_bf16(al[rt], bh[ct], acc[rt][ct], 0, 0, 0);
        acc[rt][ct] = __builtin_amdgcn_mfma_f32_16x16x32_bf16(ah[rt], bl[ct], acc[rt][ct], 0, 0, 0);
      }
    if (w == 0) {
#pragma unroll
      for (int rt = 0; rt < 4; ++rt) {
        acca[rt] = __builtin_amdgcn_mfma_f32_16x16x32_bf16(ah[rt], wh, acca[rt], 0, 0, 0);
        acca[rt] = __builtin_amdgcn_mfma_f32_16x16x32_bf16(al[rt], wh, acca[rt], 0, 0, 0);
        acca[rt] = __builtin_amdgcn_mfma_f32_16x16x32_bf16(ah[rt], wlv, acca[rt], 0, 0, 0);
      }
    }
    __syncthreads();  // stage of buf^1 complete + all reads of buf[cur] done
    cur ^= 1;
  }

  // C/D layout: col = lane&15, row = (lane>>4)*4 + reg
#pragma unroll
  for (int rt = 0; rt < 4; ++rt) {
    const int r0 = wrow + rt * 16 + lhi * 4;
#pragma unroll
    for (int ct = 0; ct < 4; ++ct) {
      const int cc = wcol + ct * 16 + llo;
#pragma unroll
      for (int e = 0; e < 4; ++e) {
        int r = r0 + e;
        if (r < N_NODES) H[(size_t)r * 256 + cc] = (_Float16)acc[rt][ct][e];
      }
    }
    if (w == 0 && llo < 8) {
#pragma unroll
      for (int e = 0; e < 4; ++e) {
        int r = r0 + e;
        if (r < N_NODES) {
          float v = acca[rt][e];
          if (llo < 4) asrc[(size_t)r * 4 + llo] = v;
          else         adst[(size_t)r * 4 + (llo - 4)] = v;
        }
      }
    }
  }
}

// ---------------- Aggregation conv1: softmax, weighted sum (fp16 gather), +b1, PReLU, -> bf16 hi/lo ----------------

__global__ __launch_bounds__(256) void k_agg1(const _Float16* __restrict__ h1,
                                              const float* __restrict__ asrc,
                                              const float* __restrict__ adst,
                                              const int* __restrict__ rowptr,
                                              const int* __restrict__ esrc,
                                              const float* __restrict__ b1,
                                              const float* __restrict__ prelu_a,
                                              unsigned short* __restrict__ out_hi,
                                              unsigned short* __restrict__ out_lo) {
  int gid = blockIdx.x * 256 + threadIdx.x;
  int dst = gid >> 6;
  int lane = threadIdx.x & 63;
  if (dst >= N_NODES) return;
  int beg = rowptr[dst], end = rowptr[dst + 1];

  float ad[4];
#pragma unroll
  for (int h = 0; h < 4; ++h) ad[h] = adst[(size_t)dst * 4 + h];

  float mh[4] = {-INFINITY, -INFINITY, -INFINITY, -INFINITY};
  for (int j = beg + lane; j < end; j += 64) {
    int s = esrc[j];
#pragma unroll
    for (int h = 0; h < 4; ++h) {
      float e = leaky(asrc[(size_t)s * 4 + h] + ad[h]);
      mh[h] = fmaxf(mh[h], e);
    }
  }
#pragma unroll
  for (int off = 1; off < 64; off <<= 1)
#pragma unroll
    for (int h = 0; h < 4; ++h) mh[h] = fmaxf(mh[h], __shfl_xor(mh[h], off));

  float dh[4] = {0.f, 0.f, 0.f, 0.f};
  for (int j = beg + lane; j < end; j += 64) {
    int s = esrc[j];
#pragma unroll
    for (int h = 0; h < 4; ++h) {
      float e = leaky(asrc[(size_t)s * 4 + h] + ad[h]);
      dh[h] += __expf(e - mh[h]);
    }
  }
#pragma unroll
  for (int off = 1; off < 64; off <<= 1)
#pragma unroll
    for (int h = 0; h < 4; ++h) dh[h] += __shfl_xor(dh[h], off);

  const int myh = lane >> 4;
  const float m_my = mh[myh];
  const float inv_my = 1.f / (dh[myh] + 1e-16f);
  const float ad_my = ad[myh];

  float4 acc = make_float4(0.f, 0.f, 0.f, 0.f);
  for (int j = beg; j < end; ++j) {
    int s = esrc[j];
    float alpha = __expf(leaky(asrc[(size_t)s * 4 + myh] + ad_my) - m_my) * inv_my;
    const half4 hv = *(const half4*)&h1[(size_t)s * 256 + 4 * lane];
    acc.x = fmaf(alpha, (float)hv[0], acc.x);
    acc.y = fmaf(alpha, (float)hv[1], acc.y);
    acc.z = fmaf(alpha, (float)hv[2], acc.z);
    acc.w = fmaf(alpha, (float)hv[3], acc.w);
  }

  const float a = prelu_a[0];
  const int c = 4 * lane;
  const float4 bv = *(const float4*)&b1[c];
  float4 r;
  r.x = acc.x + bv.x; r.x = r.x >= 0.f ? r.x : a * r.x;
  r.y = acc.y + bv.y; r.y = r.y >= 0.f ? r.y : a * r.y;
  r.z = acc.z + bv.z; r.z = r.z >= 0.f ? r.z : a * r.z;
  r.w = acc.w + bv.w; r.w = r.w >= 0.f ? r.w : a * r.w;

  ushort4 hi, lo;
  hi.x = f2bf(r.x); lo.x = f2bf(r.x - bf2f(hi.x));
  hi.y = f2bf(r.y); lo.y = f2bf(r.y - bf2f(hi.y));
  hi.z = f2bf(r.z); lo.z = f2bf(r.z - bf2f(hi.z));
  hi.w = f2bf(r.w); lo.w = f2bf(r.w - bf2f(hi.w));
  *(ushort4*)&out_hi[(size_t)dst * 256 + c] = hi;
  *(ushort4*)&out_lo[(size_t)dst * 256 + c] = lo;
}

// ---------------- Aggregation conv2: softmax, weighted sum (fp16 gather), head-mean, +b2, PReLU, @Wl+bl ----------------

__global__ __launch_bounds__(256) void k_agg2(const _Float16* __restrict__ h2,
                                              const float* __restrict__ asrc,
                                              const float* __restrict__ adst,
                                              const int* __restrict__ rowptr,
                                              const int* __restrict__ esrc,
                                              const float* __restrict__ b2,
                                              const float* __restrict__ prelu_a,
                                              const float* __restrict__ Wl,
                                              const float* __restrict__ bl,
                                              float* __restrict__ out) {
  int gid = blockIdx.x * 256 + threadIdx.x;
  int dst = gid >> 6;
  int lane = threadIdx.x & 63;
  if (dst >= N_NODES) return;
  int beg = rowptr[dst], end = rowptr[dst + 1];

  float ad[4];
#pragma unroll
  for (int h = 0; h < 4; ++h) ad[h] = adst[(size_t)dst * 4 + h];

  float mh[4] = {-INFINITY, -INFINITY, -INFINITY, -INFINITY};
  for (int j = beg + lane; j < end; j += 64) {
    int s = esrc[j];
#pragma unroll
    for (int h = 0; h < 4; ++h) {
      float e = leaky(asrc[(size_t)s * 4 + h] + ad[h]);
      mh[h] = fmaxf(mh[h], e);
    }
  }
#pragma unroll
  for (int off = 1; off < 64; off <<= 1)
#pragma unroll
    for (int h = 0; h < 4; ++h) mh[h] = fmaxf(mh[h], __shfl_xor(mh[h], off));

  float dh[4] = {0.f, 0.f, 0.f, 0.f};
  for (int j = beg + lane; j < end; j += 64) {
    int s = esrc[j];
#pragma unroll
    for (int h = 0; h < 4; ++h) {
      float e = leaky(asrc[(size_t)s * 4 + h] + ad[h]);
      dh[h] += __expf(e - mh[h]);
    }
  }
#pragma unroll
  for (int off = 1; off < 64; off <<= 1)
#pragma unroll
    for (int h = 0; h < 4; ++h) dh[h] += __shfl_xor(dh[h], off);

  const int myh = lane >> 4;
  const float m_my = mh[myh];
  const float inv_my = 1.f / (dh[myh] + 1e-16f);
  const float ad_my = ad[myh];

  float4 acc = make_float4(0.f, 0.f, 0.f, 0.f);
  for (int j = beg; j < end; ++j) {
    int s = esrc[j];
    float alpha = __expf(leaky(asrc[(size_t)s * 4 + myh] + ad_my) - m_my) * inv_my;
    const half4 hv = *(const half4*)&h2[(size_t)s * 256 + 4 * lane];
    acc.x = fmaf(alpha, (float)hv[0], acc.x);
    acc.y = fmaf(alpha, (float)hv[1], acc.y);
    acc.z = fmaf(alpha, (float)hv[2], acc.z);
    acc.w = fmaf(alpha, (float)hv[3], acc.w);
  }

#pragma unroll
  for (int off = 16; off < 64; off <<= 1) {
    acc.x += __shfl_xor(acc.x, off);
    acc.y += __shfl_xor(acc.y, off);
    acc.z += __shfl_xor(acc.z, off);
    acc.w += __shfl_xor(acc.w, off);
  }

  const float a = prelu_a[0];
  const int c0 = 4 * (lane & 15);
  float4 v;
  v.x = 0.25f * acc.x + b2[c0 + 0]; v.x = v.x >= 0.f ? v.x : a * v.x;
  v.y = 0.25f * acc.y + b2[c0 + 1]; v.y = v.y >= 0.f ? v.y : a * v.y;
  v.z = 0.25f * acc.z + b2[c0 + 2]; v.z = v.z >= 0.f ? v.z : a * v.z;
  v.w = 0.25f * acc.w + b2[c0 + 3]; v.w = v.w >= 0.f ? v.w : a * v.w;

  float p = v.x * Wl[c0 + 0] + v.y * Wl[c0 + 1] + v.z * Wl[c0 + 2] + v.w * Wl[c0 + 3];
#pragma unroll
  for (int off = 1; off < 16; off <<= 1) p += __shfl_xor(p, off);

  if (lane == 0) out[dst] = p + bl[0];
}

// ---------------- launch ----------------

static inline int cdiv(int a, int b) { return (a + b - 1) / b; }

extern "C" void kernel_launch(void* const* d_in, const int* in_sizes, int n_in,
                              void* d_out, int out_size, void* d_ws, size_t ws_size,
                              hipStream_t stream) {
  const float* x   = (const float*)d_in[0];
  const int*   ei  = (const int*)d_in[1];
  const float* W1  = (const float*)d_in[2];
  const float* as1 = (const float*)d_in[3];
  const float* ad1 = (const float*)d_in[4];
  const float* b1  = (const float*)d_in[5];
  const float* W2  = (const float*)d_in[6];
  const float* as2 = (const float*)d_in[7];
  const float* ad2 = (const float*)d_in[8];
  const float* b2  = (const float*)d_in[9];
  const float* pa  = (const float*)d_in[10];
  const float* Wl  = (const float*)d_in[11];
  const float* bl  = (const float*)d_in[12];
  float* out = (float*)d_out;

  char* ws = (char*)d_ws;
  size_t off = 0;
  auto alloc = [&](size_t bytes) -> void* {
    void* p = ws + off;
    off += (bytes + 255) & ~(size_t)255;
    return p;
  };

  _Float16* hbufA = (_Float16*)alloc((size_t)N_NODES * 256 * sizeof(_Float16)); // h1, then h2 (fp16)
  // R1: x_hi/x_lo live here during conv1; h1p_hi/h1p_lo overwrite after agg1
  unsigned short* R1 = (unsigned short*)alloc((size_t)N_NODES * 256 * 2 * sizeof(unsigned short));
  unsigned short* x_hi   = R1;                                // [N][128]
  unsigned short* x_lo   = R1 + (size_t)N_NODES * 128;
  unsigned short* h1p_hi = R1;                                // [N][256]
  unsigned short* h1p_lo = R1 + (size_t)N_NODES * 256;

  float* asrc1 = (float*)alloc((size_t)N_NODES * 4 * sizeof(float));
  float* adst1 = (float*)alloc((size_t)N_NODES * 4 * sizeof(float));
  float* asrc2 = (float*)alloc((size_t)N_NODES * 4 * sizeof(float));
  float* adst2 = (float*)alloc((size_t)N_NODES * 4 * sizeof(float));

  unsigned short* Wt1_hi  = (unsigned short*)alloc(256 * 128 * sizeof(unsigned short));
  unsigned short* Wt1_lo  = (unsigned short*)alloc(256 * 128 * sizeof(unsigned short));
  unsigned short* Wat1_hi = (unsigned short*)alloc(16 * 128 * sizeof(unsigned short));
  unsigned short* Wat1_lo = (unsigned short*)alloc(16 * 128 * sizeof(unsigned short));
  unsigned short* Wt2_hi  = (unsigned short*)alloc(256 * 256 * sizeof(unsigned short));
  unsigned short* Wt2_lo  = (unsigned short*)alloc(256 * 256 * sizeof(unsigned short));
  unsigned short* Wat2_hi = (unsigned short*)alloc(16 * 256 * sizeof(unsigned short));
  unsigned short* Wat2_lo = (unsigned short*)alloc(16 * 256 * sizeof(unsigned short));

  int* counts  = (int*)alloc((size_t)N_NODES * sizeof(int));
  int* partial = (int*)alloc((size_t)N_NODES * sizeof(int));
  int* rowptr  = (int*)alloc((size_t)(N_NODES + 1) * sizeof(int));
  int* fill    = (int*)alloc((size_t)N_NODES * sizeof(int));
  int* esrc    = (int*)alloc((size_t)E_TOT * sizeof(int));
  int* blockSums = (int*)alloc(2048 * sizeof(int));

  const int NB = cdiv(N_NODES, 256);

  // CSR build
  k_init_counts<<<NB, 256, 0, stream>>>(counts);
  k_hist<<<cdiv(N_EDGES, 256), 256, 0, stream>>>(ei, counts);
  k_scan1<<<NB, 256, 0, stream>>>(counts, partial, blockSums);
  k_scan2<<<1, 512, 0, stream>>>(blockSums, NB);
  k_scan3<<<NB, 256, 0, stream>>>(partial, blockSums, rowptr, fill);
  k_scatter<<<cdiv(E_TOT, 256), 256, 0, stream>>>(ei, fill, esrc);

  // weight prep
  k_wconv<128><<<cdiv(128 * 256, 256), 256, 0, stream>>>(W1, Wt1_hi, Wt1_lo);
  k_wa<128><<<128, 256, 0, stream>>>(W1, as1, ad1, Wat1_hi, Wat1_lo);
  k_wconv<256><<<cdiv(256 * 256, 256), 256, 0, stream>>>(W2, Wt2_hi, Wt2_lo);
  k_wa<256><<<256, 256, 0, stream>>>(W2, as2, ad2, Wat2_hi, Wat2_lo);

  // x -> bf16 hi/lo
  k_conv_x<<<N_NODES * 128 / 4 / 256, 256, 0, stream>>>(x, x_hi, x_lo);

  const int GEMM_GRID = cdiv(N_NODES, 64);  // 1563

  // conv1
  k_gemm_mfma<128><<<GEMM_GRID, 256, 0, stream>>>(x_hi, x_lo, Wt1_hi, Wt1_lo,
                                                  Wat1_hi, Wat1_lo, hbufA, asrc1, adst1);
  k_agg1<<<N_NODES * 64 / 256, 256, 0, stream>>>(hbufA, asrc1, adst1, rowptr, esrc,
                                                 b1, pa, h1p_hi, h1p_lo);

  // conv2
  k_gemm_mfma<256><<<GEMM_GRID, 256, 0, stream>>>(h1p_hi, h1p_lo, Wt2_hi, Wt2_lo,
                                                  Wat2_hi, Wat2_lo, hbufA, asrc2, adst2);
  k_agg2<<<N_NODES * 64 / 256, 256, 0, stream>>>(hbufA, asrc2, adst2, rowptr, esrc,
                                                 b2, pa, Wl, bl, out);
}

// Round 6
// 412.501 us; speedup vs baseline: 1.9585x; 1.0655x over previous
//
#include <hip/hip_runtime.h>
#include <cstdint>
#include <cstddef>

static constexpr int N_NODES = 100000;
static constexpr int N_EDGES = 600000;
static constexpr int E_TOT   = N_EDGES + N_NODES;
static constexpr float NEG_SLOPE = 0.2f;

typedef __attribute__((ext_vector_type(8))) short bf16x8;   // 8 bf16 (4 VGPR)
typedef __attribute__((ext_vector_type(4))) float f32x4;    // 4 fp32
typedef __attribute__((ext_vector_type(4))) _Float16 half4; // 4 fp16 (8B)

__device__ __forceinline__ float leaky(float x) { return x >= 0.f ? x : NEG_SLOPE * x; }

__device__ __forceinline__ unsigned short f2bf(float f) {  // RNE to bf16
  unsigned u = __float_as_uint(f);
  u = u + 0x7fffu + ((u >> 16) & 1u);
  return (unsigned short)(u >> 16);
}
__device__ __forceinline__ float bf2f(unsigned short h) {
  return __uint_as_float((unsigned)h << 16);
}

// async global -> LDS, 16 bytes per lane. Dest is wave-uniform base + lane*16.
__device__ __forceinline__ void gload16(const unsigned short* g, unsigned short* l) {
  __builtin_amdgcn_global_load_lds(
      (const __attribute__((address_space(1))) unsigned int*)g,
      (__attribute__((address_space(3))) unsigned int*)l,
      16, 0, 0);
}

// ---------------- CSR build ----------------

__global__ __launch_bounds__(256) void k_init_counts(int* __restrict__ counts) {
  int i = blockIdx.x * 256 + threadIdx.x;
  if (i < N_NODES) counts[i] = 1;   // self-loop
}

__global__ __launch_bounds__(256) void k_hist(const int* __restrict__ ei, int* __restrict__ counts) {
  int e = blockIdx.x * 256 + threadIdx.x;
  if (e < N_EDGES) atomicAdd(&counts[ei[N_EDGES + e]], 1);
}

__global__ __launch_bounds__(256) void k_scan1(const int* __restrict__ counts,
                                               int* __restrict__ partial,
                                               int* __restrict__ blockSums) {
  __shared__ int tmp[256];
  int tid = threadIdx.x;
  int i = blockIdx.x * 256 + tid;
  int v = (i < N_NODES) ? counts[i] : 0;
  tmp[tid] = v;
  __syncthreads();
  for (int off = 1; off < 256; off <<= 1) {
    int t = (tid >= off) ? tmp[tid - off] : 0;
    __syncthreads();
    tmp[tid] += t;
    __syncthreads();
  }
  if (i < N_NODES) partial[i] = tmp[tid] - v;
  if (tid == 255) blockSums[blockIdx.x] = tmp[tid];
}

__global__ __launch_bounds__(512) void k_scan2(int* __restrict__ blockSums, int nb) {
  __shared__ int tmp[512];
  int tid = threadIdx.x;
  int v = (tid < nb) ? blockSums[tid] : 0;
  tmp[tid] = v;
  __syncthreads();
  for (int off = 1; off < 512; off <<= 1) {
    int t = (tid >= off) ? tmp[tid - off] : 0;
    __syncthreads();
    tmp[tid] += t;
    __syncthreads();
  }
  if (tid < nb) blockSums[tid] = tmp[tid] - v;
}

__global__ __launch_bounds__(256) void k_scan3(const int* __restrict__ partial,
                                               const int* __restrict__ blockSums,
                                               int* __restrict__ rowptr,
                                               int* __restrict__ fill) {
  int i = blockIdx.x * 256 + threadIdx.x;
  if (i < N_NODES) {
    int v = partial[i] + blockSums[blockIdx.x];
    rowptr[i] = v;
    fill[i] = v;
  }
  if (i == 0) rowptr[N_NODES] = E_TOT;
}

__global__ __launch_bounds__(256) void k_scatter(const int* __restrict__ ei,
                                                 int* __restrict__ fill,
                                                 int* __restrict__ esrc) {
  int i = blockIdx.x * 256 + threadIdx.x;
  if (i >= E_TOT) return;
  int s, d;
  if (i < N_EDGES) { s = ei[i]; d = ei[N_EDGES + i]; }
  else             { s = i - N_EDGES; d = s; }
  int pos = atomicAdd(&fill[d], 1);
  esrc[pos] = s;
}

// ---------------- weight prep ----------------

template <int K>
__global__ __launch_bounds__(256) void k_wconv(const float* __restrict__ W,
                                               unsigned short* __restrict__ Wt_hi,
                                               unsigned short* __restrict__ Wt_lo) {
  int t = blockIdx.x * 256 + threadIdx.x;
  if (t >= K * 256) return;
  int k = t >> 8, c = t & 255;
  float v = W[t];
  unsigned short hi = f2bf(v);
  Wt_hi[(size_t)c * K + k] = hi;
  Wt_lo[(size_t)c * K + k] = f2bf(v - bf2f(hi));
}

template <int K>
__global__ __launch_bounds__(256) void k_wa(const float* __restrict__ W,
                                            const float* __restrict__ att_s,
                                            const float* __restrict__ att_d,
                                            unsigned short* __restrict__ Wat_hi,
                                            unsigned short* __restrict__ Wat_lo) {
  int k = blockIdx.x;
  int h = threadIdx.x >> 6, c = threadIdx.x & 63;
  float wv = W[(size_t)k * 256 + h * 64 + c];
  float ps = wv * att_s[h * 64 + c];
  float pd = wv * att_d[h * 64 + c];
#pragma unroll
  for (int off = 32; off > 0; off >>= 1) {
    ps += __shfl_xor(ps, off);
    pd += __shfl_xor(pd, off);
  }
  if (c == 0) {
    unsigned short hi = f2bf(ps);
    Wat_hi[(size_t)h * K + k] = hi;
    Wat_lo[(size_t)h * K + k] = f2bf(ps - bf2f(hi));
    hi = f2bf(pd);
    Wat_hi[(size_t)(4 + h) * K + k] = hi;
    Wat_lo[(size_t)(4 + h) * K + k] = f2bf(pd - bf2f(hi));
  }
  if (threadIdx.x >= 8 && threadIdx.x < 16) {
    Wat_hi[(size_t)threadIdx.x * K + k] = 0;
    Wat_lo[(size_t)threadIdx.x * K + k] = 0;
  }
}

// ---------------- x -> bf16 hi/lo ----------------

__global__ __launch_bounds__(256) void k_conv_x(const float* __restrict__ X,
                                                unsigned short* __restrict__ Xhi,
                                                unsigned short* __restrict__ Xlo) {
  size_t t = (size_t)blockIdx.x * 256 + threadIdx.x;  // handles 4 floats
  float4 v = *(const float4*)&X[t * 4];
  ushort4 hi, lo;
  hi.x = f2bf(v.x); lo.x = f2bf(v.x - bf2f(hi.x));
  hi.y = f2bf(v.y); lo.y = f2bf(v.y - bf2f(hi.y));
  hi.z = f2bf(v.z); lo.z = f2bf(v.z - bf2f(hi.z));
  hi.w = f2bf(v.w); lo.w = f2bf(v.w - bf2f(hi.w));
  *(ushort4*)&Xhi[t * 4] = hi;
  *(ushort4*)&Xlo[t * 4] = lo;
}

// ---------------- MFMA GEMM: H[N,256] = A[N,K] @ W[K,256], split bf16 hi/lo ----------------
// 2-phase pipeline, double-buffered LDS via global_load_lds (width 16). See r4 notes.

template <int K>
__global__ __launch_bounds__(256, 2) void k_gemm_mfma(
    const unsigned short* __restrict__ Ahi, const unsigned short* __restrict__ Alo,
    const unsigned short* __restrict__ Bhi, const unsigned short* __restrict__ Blo,
    const unsigned short* __restrict__ Whi, const unsigned short* __restrict__ Wlo,
    _Float16* __restrict__ H, float* __restrict__ asrc, float* __restrict__ adst) {
  __shared__ __align__(16) unsigned short lds[2][20480];   // 80 KB

  const int tid = threadIdx.x;
  const int w = tid >> 6, lane = tid & 63;
  const int lhi = lane >> 4, llo = lane & 15;
  const int wrow = blockIdx.x * 64;
  const int wcol = w * 64;

  const int sr = tid >> 2;                 // tile row handled by this thread (0..63)
  const int sc = (tid & 3) ^ (sr & 3);     // swizzled source chunk
  int ar = wrow + sr; if (ar > N_NODES - 1) ar = N_NODES - 1;
  const unsigned short* gAh = &Ahi[(size_t)ar * K + sc * 8];
  const unsigned short* gAl = &Alo[(size_t)ar * K + sc * 8];
  const unsigned short* gB0h = &Bhi[(size_t)(0 * 64 + sr) * K + sc * 8];
  const unsigned short* gB1h = &Bhi[(size_t)(1 * 64 + sr) * K + sc * 8];
  const unsigned short* gB2h = &Bhi[(size_t)(2 * 64 + sr) * K + sc * 8];
  const unsigned short* gB3h = &Bhi[(size_t)(3 * 64 + sr) * K + sc * 8];
  const unsigned short* gB0l = &Blo[(size_t)(0 * 64 + sr) * K + sc * 8];
  const unsigned short* gB1l = &Blo[(size_t)(1 * 64 + sr) * K + sc * 8];
  const unsigned short* gB2l = &Blo[(size_t)(2 * 64 + sr) * K + sc * 8];
  const unsigned short* gB3l = &Blo[(size_t)(3 * 64 + sr) * K + sc * 8];
  const int wb = w * 512;                  // per-wave dest base offset (shorts)

  const unsigned short* gWh = &Whi[(size_t)llo * K + lhi * 8];
  const unsigned short* gWl = &Wlo[(size_t)llo * K + lhi * 8];

  f32x4 acc[4][4] = {};
  f32x4 acca[4] = {};

  const int ach = (lhi ^ (llo & 3)) * 8;

  auto STAGE = [&](int buf, int kc) {
    unsigned short* L = lds[buf];
    gload16(gAh + kc, L + 0 + wb);
    gload16(gAl + kc, L + 2048 + wb);
    gload16(gB0h + kc, L + 4096 + 0 * 2048 + wb);
    gload16(gB1h + kc, L + 4096 + 1 * 2048 + wb);
    gload16(gB2h + kc, L + 4096 + 2 * 2048 + wb);
    gload16(gB3h + kc, L + 4096 + 3 * 2048 + wb);
    gload16(gB0l + kc, L + 12288 + 0 * 2048 + wb);
    gload16(gB1l + kc, L + 12288 + 1 * 2048 + wb);
    gload16(gB2l + kc, L + 12288 + 2 * 2048 + wb);
    gload16(gB3l + kc, L + 12288 + 3 * 2048 + wb);
  };

  STAGE(0, 0);
  __syncthreads();

  constexpr int NT = K / 32;
  int cur = 0;
#pragma unroll 2
  for (int t = 0; t < NT; ++t) {
    if (t + 1 < NT) STAGE(cur ^ 1, (t + 1) * 32);

    bf16x8 wh{}, wlv{};
    if (w == 0) {
      wh  = *(const bf16x8*)&gWh[t * 32];
      wlv = *(const bf16x8*)&gWl[t * 32];
    }

    const unsigned short* L = lds[cur];
    bf16x8 ah[4], al[4], bh[4], bl[4];
#pragma unroll
    for (int rt = 0; rt < 4; ++rt) {
      ah[rt] = *(const bf16x8*)&L[(rt * 16 + llo) * 32 + ach];
      al[rt] = *(const bf16x8*)&L[2048 + (rt * 16 + llo) * 32 + ach];
    }
#pragma unroll
    for (int ct = 0; ct < 4; ++ct) {
      bh[ct] = *(const bf16x8*)&L[4096 + (wcol + ct * 16 + llo) * 32 + ach];
      bl[ct] = *(const bf16x8*)&L[12288 + (wcol + ct * 16 + llo) * 32 + ach];
    }

#pragma unroll
    for (int ct = 0; ct < 4; ++ct)
#pragma unroll
      for (int rt = 0; rt < 4; ++rt) {
        acc[rt][ct] = __builtin_amdgcn_mfma_f32_16x16x32_bf16(ah[rt], bh[ct], acc[rt][ct], 0, 0, 0);
        acc[rt][ct] = __builtin_amdgcn_mfma_f32_16x16x32_bf16(al[rt], bh[ct], acc[rt][ct], 0, 0, 0);
        acc[rt][ct] = __builtin_amdgcn_mfma_f32_16x16x32_bf16(ah[rt], bl[ct], acc[rt][ct], 0, 0, 0);
      }
    if (w == 0) {
#pragma unroll
      for (int rt = 0; rt < 4; ++rt) {
        acca[rt] = __builtin_amdgcn_mfma_f32_16x16x32_bf16(ah[rt], wh, acca[rt], 0, 0, 0);
        acca[rt] = __builtin_amdgcn_mfma_f32_16x16x32_bf16(al[rt], wh, acca[rt], 0, 0, 0);
        acca[rt] = __builtin_amdgcn_mfma_f32_16x16x32_bf16(ah[rt], wlv, acca[rt], 0, 0, 0);
      }
    }
    __syncthreads();
    cur ^= 1;
  }

  // C/D layout: col = lane&15, row = (lane>>4)*4 + reg
#pragma unroll
  for (int rt = 0; rt < 4; ++rt) {
    const int r0 = wrow + rt * 16 + lhi * 4;
#pragma unroll
    for (int ct = 0; ct < 4; ++ct) {
      const int cc = wcol + ct * 16 + llo;
#pragma unroll
      for (int e = 0; e < 4; ++e) {
        int r = r0 + e;
        if (r < N_NODES) H[(size_t)r * 256 + cc] = (_Float16)acc[rt][ct][e];
      }
    }
    if (w == 0 && llo < 8) {
#pragma unroll
      for (int e = 0; e < 4; ++e) {
        int r = r0 + e;
        if (r < N_NODES) {
          float v = acca[rt][e];
          if (llo < 4) asrc[(size_t)r * 4 + llo] = v;
          else         adst[(size_t)r * 4 + (llo - 4)] = v;
        }
      }
    }
  }
}

// ---------------- softmax stats: one thread per (dst, head) ----------------
// Writes unnormalized p[j][h] = exp(e - m) per edge, and dinv[d][h] = 1/(denom+1e-16).

__global__ __launch_bounds__(256) void k_stats(const float* __restrict__ asrc,
                                               const float* __restrict__ adst,
                                               const int* __restrict__ rowptr,
                                               const int* __restrict__ esrc,
                                               float* __restrict__ pbuf,
                                               float* __restrict__ dinv) {
  int t = blockIdx.x * 256 + threadIdx.x;
  int d = t >> 2, h = t & 3;
  if (d >= N_NODES) return;
  const int beg = rowptr[d], end = rowptr[d + 1];
  const float ad = adst[(size_t)d * 4 + h];

  float m = -INFINITY;
  for (int j = beg; j < end; ++j) {
    float e = leaky(asrc[(size_t)esrc[j] * 4 + h] + ad);
    m = fmaxf(m, e);
  }
  float den = 0.f;
  for (int j = beg; j < end; ++j) {
    float p = __expf(leaky(asrc[(size_t)esrc[j] * 4 + h] + ad) - m);
    den += p;
    pbuf[(size_t)j * 4 + h] = p;
  }
  dinv[(size_t)d * 4 + h] = 1.f / (den + 1e-16f);
}

// ---------------- gather conv1: pure weighted gather, scale, +b1, PReLU, -> bf16 hi/lo ----------------
// One wave per dst; lane l owns channels [4l..4l+3]; head = l>>4.

__global__ __launch_bounds__(256) void k_agg1(const _Float16* __restrict__ h1,
                                              const float* __restrict__ pbuf,
                                              const float* __restrict__ dinv,
                                              const int* __restrict__ rowptr,
                                              const int* __restrict__ esrc,
                                              const float* __restrict__ b1,
                                              const float* __restrict__ prelu_a,
                                              unsigned short* __restrict__ out_hi,
                                              unsigned short* __restrict__ out_lo) {
  int gid = blockIdx.x * 256 + threadIdx.x;
  int dst = gid >> 6;
  int lane = threadIdx.x & 63;
  if (dst >= N_NODES) return;
  const int beg = rowptr[dst], end = rowptr[dst + 1];
  const int myh = lane >> 4;

  float4 acc = make_float4(0.f, 0.f, 0.f, 0.f);
  for (int j = beg; j < end; ++j) {
    int s = esrc[j];
    float p = pbuf[(size_t)j * 4 + myh];
    const half4 hv = *(const half4*)&h1[(size_t)s * 256 + 4 * lane];
    acc.x = fmaf(p, (float)hv[0], acc.x);
    acc.y = fmaf(p, (float)hv[1], acc.y);
    acc.z = fmaf(p, (float)hv[2], acc.z);
    acc.w = fmaf(p, (float)hv[3], acc.w);
  }
  const float sc = dinv[(size_t)dst * 4 + myh];
  acc.x *= sc; acc.y *= sc; acc.z *= sc; acc.w *= sc;

  const float a = prelu_a[0];
  const int c = 4 * lane;
  const float4 bv = *(const float4*)&b1[c];
  float4 r;
  r.x = acc.x + bv.x; r.x = r.x >= 0.f ? r.x : a * r.x;
  r.y = acc.y + bv.y; r.y = r.y >= 0.f ? r.y : a * r.y;
  r.z = acc.z + bv.z; r.z = r.z >= 0.f ? r.z : a * r.z;
  r.w = acc.w + bv.w; r.w = r.w >= 0.f ? r.w : a * r.w;

  ushort4 hi, lo;
  hi.x = f2bf(r.x); lo.x = f2bf(r.x - bf2f(hi.x));
  hi.y = f2bf(r.y); lo.y = f2bf(r.y - bf2f(hi.y));
  hi.z = f2bf(r.z); lo.z = f2bf(r.z - bf2f(hi.z));
  hi.w = f2bf(r.w); lo.w = f2bf(r.w - bf2f(hi.w));
  *(ushort4*)&out_hi[(size_t)dst * 256 + c] = hi;
  *(ushort4*)&out_lo[(size_t)dst * 256 + c] = lo;
}

// ---------------- gather conv2: weighted gather, scale, head-mean, +b2, PReLU, @Wl+bl ----------------

__global__ __launch_bounds__(256) void k_agg2(const _Float16* __restrict__ h2,
                                              const float* __restrict__ pbuf,
                                              const float* __restrict__ dinv,
                                              const int* __restrict__ rowptr,
                                              const int* __restrict__ esrc,
                                              const float* __restrict__ b2,
                                              const float* __restrict__ prelu_a,
                                              const float* __restrict__ Wl,
                                              const float* __restrict__ bl,
                                              float* __restrict__ out) {
  int gid = blockIdx.x * 256 + threadIdx.x;
  int dst = gid >> 6;
  int lane = threadIdx.x & 63;
  if (dst >= N_NODES) return;
  const int beg = rowptr[dst], end = rowptr[dst + 1];
  const int myh = lane >> 4;

  float4 acc = make_float4(0.f, 0.f, 0.f, 0.f);
  for (int j = beg; j < end; ++j) {
    int s = esrc[j];
    float p = pbuf[(size_t)j * 4 + myh];
    const half4 hv = *(const half4*)&h2[(size_t)s * 256 + 4 * lane];
    acc.x = fmaf(p, (float)hv[0], acc.x);
    acc.y = fmaf(p, (float)hv[1], acc.y);
    acc.z = fmaf(p, (float)hv[2], acc.z);
    acc.w = fmaf(p, (float)hv[3], acc.w);
  }
  const float sc = dinv[(size_t)dst * 4 + myh];
  acc.x *= sc; acc.y *= sc; acc.z *= sc; acc.w *= sc;

  // head-mean: lanes {l, l+16, l+32, l+48} hold heads 0..3 for channel group 4*(l&15)
#pragma unroll
  for (int off = 16; off < 64; off <<= 1) {
    acc.x += __shfl_xor(acc.x, off);
    acc.y += __shfl_xor(acc.y, off);
    acc.z += __shfl_xor(acc.z, off);
    acc.w += __shfl_xor(acc.w, off);
  }

  const float a = prelu_a[0];
  const int c0 = 4 * (lane & 15);
  float4 v;
  v.x = 0.25f * acc.x + b2[c0 + 0]; v.x = v.x >= 0.f ? v.x : a * v.x;
  v.y = 0.25f * acc.y + b2[c0 + 1]; v.y = v.y >= 0.f ? v.y : a * v.y;
  v.z = 0.25f * acc.z + b2[c0 + 2]; v.z = v.z >= 0.f ? v.z : a * v.z;
  v.w = 0.25f * acc.w + b2[c0 + 3]; v.w = v.w >= 0.f ? v.w : a * v.w;

  float p = v.x * Wl[c0 + 0] + v.y * Wl[c0 + 1] + v.z * Wl[c0 + 2] + v.w * Wl[c0 + 3];
#pragma unroll
  for (int off = 1; off < 16; off <<= 1) p += __shfl_xor(p, off);

  if (lane == 0) out[dst] = p + bl[0];
}

// ---------------- launch ----------------

static inline int cdiv(int a, int b) { return (a + b - 1) / b; }

extern "C" void kernel_launch(void* const* d_in, const int* in_sizes, int n_in,
                              void* d_out, int out_size, void* d_ws, size_t ws_size,
                              hipStream_t stream) {
  const float* x   = (const float*)d_in[0];
  const int*   ei  = (const int*)d_in[1];
  const float* W1  = (const float*)d_in[2];
  const float* as1 = (const float*)d_in[3];
  const float* ad1 = (const float*)d_in[4];
  const float* b1  = (const float*)d_in[5];
  const float* W2  = (const float*)d_in[6];
  const float* as2 = (const float*)d_in[7];
  const float* ad2 = (const float*)d_in[8];
  const float* b2  = (const float*)d_in[9];
  const float* pa  = (const float*)d_in[10];
  const float* Wl  = (const float*)d_in[11];
  const float* bl  = (const float*)d_in[12];
  float* out = (float*)d_out;

  char* ws = (char*)d_ws;
  size_t off = 0;
  auto alloc = [&](size_t bytes) -> void* {
    void* p = ws + off;
    off += (bytes + 255) & ~(size_t)255;
    return p;
  };

  _Float16* hbufA = (_Float16*)alloc((size_t)N_NODES * 256 * sizeof(_Float16)); // h1, then h2 (fp16)
  // R1: x_hi/x_lo live here during conv1; h1p_hi/h1p_lo overwrite after agg1
  unsigned short* R1 = (unsigned short*)alloc((size_t)N_NODES * 256 * 2 * sizeof(unsigned short));
  unsigned short* x_hi   = R1;                                // [N][128]
  unsigned short* x_lo   = R1 + (size_t)N_NODES * 128;
  unsigned short* h1p_hi = R1;                                // [N][256]
  unsigned short* h1p_lo = R1 + (size_t)N_NODES * 256;

  float* asrc1 = (float*)alloc((size_t)N_NODES * 4 * sizeof(float));
  float* adst1 = (float*)alloc((size_t)N_NODES * 4 * sizeof(float));
  float* asrc2 = (float*)alloc((size_t)N_NODES * 4 * sizeof(float));
  float* adst2 = (float*)alloc((size_t)N_NODES * 4 * sizeof(float));
  float* pbuf  = (float*)alloc((size_t)E_TOT * 4 * sizeof(float));   // per-edge exp, reused
  float* dinv  = (float*)alloc((size_t)N_NODES * 4 * sizeof(float)); // per-(dst,head) 1/denom, reused

  unsigned short* Wt1_hi  = (unsigned short*)alloc(256 * 128 * sizeof(unsigned short));
  unsigned short* Wt1_lo  = (unsigned short*)alloc(256 * 128 * sizeof(unsigned short));
  unsigned short* Wat1_hi = (unsigned short*)alloc(16 * 128 * sizeof(unsigned short));
  unsigned short* Wat1_lo = (unsigned short*)alloc(16 * 128 * sizeof(unsigned short));
  unsigned short* Wt2_hi  = (unsigned short*)alloc(256 * 256 * sizeof(unsigned short));
  unsigned short* Wt2_lo  = (unsigned short*)alloc(256 * 256 * sizeof(unsigned short));
  unsigned short* Wat2_hi = (unsigned short*)alloc(16 * 256 * sizeof(unsigned short));
  unsigned short* Wat2_lo = (unsigned short*)alloc(16 * 256 * sizeof(unsigned short));

  int* counts  = (int*)alloc((size_t)N_NODES * sizeof(int));
  int* partial = (int*)alloc((size_t)N_NODES * sizeof(int));
  int* rowptr  = (int*)alloc((size_t)(N_NODES + 1) * sizeof(int));
  int* fill    = (int*)alloc((size_t)N_NODES * sizeof(int));
  int* esrc    = (int*)alloc((size_t)E_TOT * sizeof(int));
  int* blockSums = (int*)alloc(2048 * sizeof(int));

  const int NB = cdiv(N_NODES, 256);

  // CSR build
  k_init_counts<<<NB, 256, 0, stream>>>(counts);
  k_hist<<<cdiv(N_EDGES, 256), 256, 0, stream>>>(ei, counts);
  k_scan1<<<NB, 256, 0, stream>>>(counts, partial, blockSums);
  k_scan2<<<1, 512, 0, stream>>>(blockSums, NB);
  k_scan3<<<NB, 256, 0, stream>>>(partial, blockSums, rowptr, fill);
  k_scatter<<<cdiv(E_TOT, 256), 256, 0, stream>>>(ei, fill, esrc);

  // weight prep
  k_wconv<128><<<cdiv(128 * 256, 256), 256, 0, stream>>>(W1, Wt1_hi, Wt1_lo);
  k_wa<128><<<128, 256, 0, stream>>>(W1, as1, ad1, Wat1_hi, Wat1_lo);
  k_wconv<256><<<cdiv(256 * 256, 256), 256, 0, stream>>>(W2, Wt2_hi, Wt2_lo);
  k_wa<256><<<256, 256, 0, stream>>>(W2, as2, ad2, Wat2_hi, Wat2_lo);

  // x -> bf16 hi/lo
  k_conv_x<<<N_NODES * 128 / 4 / 256, 256, 0, stream>>>(x, x_hi, x_lo);

  const int GEMM_GRID = cdiv(N_NODES, 64);  // 1563
  const int STATS_GRID = cdiv(N_NODES * 4, 256);

  // conv1
  k_gemm_mfma<128><<<GEMM_GRID, 256, 0, stream>>>(x_hi, x_lo, Wt1_hi, Wt1_lo,
                                                  Wat1_hi, Wat1_lo, hbufA, asrc1, adst1);
  k_stats<<<STATS_GRID, 256, 0, stream>>>(asrc1, adst1, rowptr, esrc, pbuf, dinv);
  k_agg1<<<N_NODES * 64 / 256, 256, 0, stream>>>(hbufA, pbuf, dinv, rowptr, esrc,
                                                 b1, pa, h1p_hi, h1p_lo);

  // conv2
  k_gemm_mfma<256><<<GEMM_GRID, 256, 0, stream>>>(h1p_hi, h1p_lo, Wt2_hi, Wt2_lo,
                                                  Wat2_hi, Wat2_lo, hbufA, asrc2, adst2);
  k_stats<<<STATS_GRID, 256, 0, stream>>>(asrc2, adst2, rowptr, esrc, pbuf, dinv);
  k_agg2<<<N_NODES * 64 / 256, 256, 0, stream>>>(hbufA, pbuf, dinv, rowptr, esrc,
                                                 b2, pa, Wl, bl, out);
}